// Round 2
// baseline (1942.448 us; speedup 1.0000x reference)
//
#include <hip/hip_runtime.h>
#include <math.h>

#define CD 512
#define CDCD (CD * CD)
#define QN 8000
#define UN 20000
#define BATCHN 128

// ================= GEMM: C[n x 512] = A[n x 512] @ B[512 x 512] =================
// Optional second (B1,C1) pair sharing the same A (launch grid.y = 8 instead of 4).
#define GBM 128
#define GBN 128
#define GBK 16

__global__ __launch_bounds__(256) void gemm_f32(
    const float* __restrict__ A, int n,
    const float* __restrict__ B0, float* __restrict__ C0,
    const float* __restrict__ B1, float* __restrict__ C1)
{
    __shared__ __align__(16) float As[GBK][GBM];
    __shared__ __align__(16) float Bs[GBK][GBN];
    const int which = blockIdx.y >> 2;
    const float* __restrict__ B = which ? B1 : B0;
    float* __restrict__ C = which ? C1 : C0;
    const int bm = blockIdx.x * GBM, bn = (blockIdx.y & 3) * GBN;
    const int tid = threadIdx.x;
    const int tx = tid & 15, ty = tid >> 4;
    const int arow = tid >> 1, akq = (tid & 1) * 8;
    const int bkr = tid >> 4, bcol = (tid & 15) * 8;
    const int gr = bm + arow;
    const bool aok = (gr < n);
    const float* Arow = A + (size_t)(aok ? gr : 0) * CD;

    float acc[8][8];
#pragma unroll
    for (int i = 0; i < 8; i++)
#pragma unroll
        for (int j = 0; j < 8; j++) acc[i][j] = 0.f;

    for (int k0 = 0; k0 < CD; k0 += GBK) {
        float4 av0 = make_float4(0.f, 0.f, 0.f, 0.f), av1 = av0;
        if (aok) {
            av0 = *(const float4*)(Arow + k0 + akq);
            av1 = *(const float4*)(Arow + k0 + akq + 4);
        }
        float4 bv0 = *(const float4*)(B + (size_t)(k0 + bkr) * CD + bn + bcol);
        float4 bv1 = *(const float4*)(B + (size_t)(k0 + bkr) * CD + bn + bcol + 4);
        __syncthreads();
        As[akq + 0][arow] = av0.x; As[akq + 1][arow] = av0.y;
        As[akq + 2][arow] = av0.z; As[akq + 3][arow] = av0.w;
        As[akq + 4][arow] = av1.x; As[akq + 5][arow] = av1.y;
        As[akq + 6][arow] = av1.z; As[akq + 7][arow] = av1.w;
        *(float4*)&Bs[bkr][bcol]     = bv0;
        *(float4*)&Bs[bkr][bcol + 4] = bv1;
        __syncthreads();
#pragma unroll
        for (int kk = 0; kk < GBK; kk++) {
            float a0[8], b0[8];
            *(float4*)&a0[0] = *(const float4*)&As[kk][ty * 8];
            *(float4*)&a0[4] = *(const float4*)&As[kk][ty * 8 + 4];
            *(float4*)&b0[0] = *(const float4*)&Bs[kk][tx * 8];
            *(float4*)&b0[4] = *(const float4*)&Bs[kk][tx * 8 + 4];
#pragma unroll
            for (int i = 0; i < 8; i++)
#pragma unroll
                for (int j = 0; j < 8; j++)
                    acc[i][j] = fmaf(a0[i], b0[j], acc[i][j]);
        }
    }
    const int orow = bm + ty * 8, ocol = bn + tx * 8;
#pragma unroll
    for (int i = 0; i < 8; i++) {
        int r = orow + i;
        if (r < n) {
            *(float4*)(C + (size_t)r * CD + ocol) =
                make_float4(acc[i][0], acc[i][1], acc[i][2], acc[i][3]);
            *(float4*)(C + (size_t)r * CD + ocol + 4) =
                make_float4(acc[i][4], acc[i][5], acc[i][6], acc[i][7]);
        }
    }
}

// ========== dot_rows: out[r] = H[sel?sel[r]:r] . v   (one wave per row) ==========
__global__ __launch_bounds__(256) void dot_rows(
    const float* __restrict__ H, const int* __restrict__ sel,
    const float* __restrict__ v, float* __restrict__ out, int n)
{
    const int lane = threadIdx.x & 63;
    const int r = blockIdx.x * 4 + (threadIdx.x >> 6);
    if (r >= n) return;
    const int row = sel ? sel[r] : r;
    const float* h = H + (size_t)row * CD;
    float4 a0 = *(const float4*)(h + lane * 8);
    float4 a1 = *(const float4*)(h + lane * 8 + 4);
    float4 b0 = *(const float4*)(v + lane * 8);
    float4 b1 = *(const float4*)(v + lane * 8 + 4);
    float sv = a0.x * b0.x + a0.y * b0.y + a0.z * b0.z + a0.w * b0.w
             + a1.x * b1.x + a1.y * b1.y + a1.z * b1.z + a1.w * b1.w;
#pragma unroll
    for (int o = 32; o; o >>= 1) sv += __shfl_xor(sv, o, 64);
    if (lane == 0) out[r] = sv;
}

// ========== wa_gemv6: wa[l][k] = sum_j W[l][k][j] * a[l][CD + j], l = 0..5 ==========
__global__ __launch_bounds__(256) void wa_gemv6(
    const float* __restrict__ W6, const float* __restrict__ a6, float* __restrict__ wa)
{
    const int layer = blockIdx.y;
    const int lane = threadIdx.x & 63;
    const int r = blockIdx.x * 4 + (threadIdx.x >> 6);   // 0..511 (grid.x = 128)
    const float* Wr = W6 + (size_t)layer * CDCD + (size_t)r * CD;
    const float* ah = a6 + layer * 2 * CD + CD;
    float4 a0 = *(const float4*)(Wr + lane * 8);
    float4 a1 = *(const float4*)(Wr + lane * 8 + 4);
    float4 b0 = *(const float4*)(ah + lane * 8);
    float4 b1 = *(const float4*)(ah + lane * 8 + 4);
    float sv = a0.x * b0.x + a0.y * b0.y + a0.z * b0.z + a0.w * b0.w
             + a1.x * b1.x + a1.y * b1.y + a1.z * b1.z + a1.w * b1.w;
#pragma unroll
    for (int o = 32; o; o >>= 1) sv += __shfl_xor(sv, o, 64);
    if (lane == 0) wa[layer * CD + r] = sv;
}

// ================= CSR build (one block per graph) =================
struct CsrJob {
    const int* src; const int* dst;
    int n_edges; int n_dst; int dst_base;
    int* off; int* srcs;
};
struct CsrJobs { CsrJob j[6]; };

__global__ __launch_bounds__(1024) void build_csr(CsrJobs jobs)
{
    __shared__ int cnt[UN];
    __shared__ int wsum[16];
    CsrJob jb = jobs.j[blockIdx.x];
    const int tid = threadIdx.x;
    const int lane = tid & 63, wid = tid >> 6;
    const int n = jb.n_dst;

    for (int i = tid; i < n; i += 1024) cnt[i] = 0;
    __syncthreads();
    for (int e = tid; e < jb.n_edges; e += 1024)
        atomicAdd(&cnt[jb.dst[e] - jb.dst_base], 1);
    __syncthreads();

    int running = 0;
    for (int base = 0; base < n; base += 1024) {
        int idx = base + tid;
        int v0 = (idx < n) ? cnt[idx] : 0;
        int v = v0;
#pragma unroll
        for (int dlt = 1; dlt < 64; dlt <<= 1) {
            int t = __shfl_up(v, dlt, 64);
            if (lane >= dlt) v += t;
        }
        if (lane == 63) wsum[wid] = v;
        __syncthreads();
        if (wid == 0) {
            int wv = (lane < 16) ? wsum[lane] : 0;
#pragma unroll
            for (int dlt = 1; dlt < 16; dlt <<= 1) {
                int t = __shfl_up(wv, dlt, 64);
                if (lane >= dlt) wv += t;
            }
            if (lane < 16) wsum[lane] = wv;
        }
        __syncthreads();
        int wprefix = (wid > 0) ? wsum[wid - 1] : 0;
        int chunk_total = wsum[15];
        int excl = running + wprefix + (v - v0);
        if (idx < n) { jb.off[idx] = excl; cnt[idx] = excl; }
        running += chunk_total;
        __syncthreads();
    }
    if (tid == 0) jb.off[n] = running;
    // scatter (cnt[] now holds running cursors at exclusive offsets)
    for (int e = tid; e < jb.n_edges; e += 1024) {
        int dl = jb.dst[e] - jb.dst_base;
        int pos = atomicAdd(&cnt[dl], 1);
        jb.srcs[pos] = jb.src[e];
    }
}

// ================= GAT aggregate: one block per (possibly selected) dst node ======
// node = sel?sel[b]:b ; edges via CSR[node]; local src index = srcs[e]-src_base.
// score = lrelu(s[src_local] + dvals[b]); out[b] = base[node] + sum alpha * z[src_local]
__global__ __launch_bounds__(256) void gat_aggregate(
    const int* __restrict__ off, const int* __restrict__ srcs, int src_base,
    const int* __restrict__ sel,
    const float* __restrict__ z, const float* __restrict__ s,
    const float* __restrict__ dvals,
    const float* __restrict__ base, float* __restrict__ out)
{
    const int b = blockIdx.x;
    const int node = sel ? sel[b] : b;
    const int tid = threadIdx.x;
    const int lane = tid & 63, wid = tid >> 6;
    const int beg = off[node], end = off[node + 1];

    float2 bacc = base ? *(const float2*)(base + (size_t)node * CD + tid * 2)
                       : make_float2(0.f, 0.f);
    if (beg == end) {
        *(float2*)(out + (size_t)b * CD + tid * 2) = bacc;
        return;
    }
    const float dd = dvals[b];

    // online softmax stats over this thread's edge subset
    float m = -1e30f, den = 0.f;
    for (int e = beg + tid; e < end; e += 256) {
        float sc = s[srcs[e] - src_base] + dd;
        sc = sc > 0.f ? sc : 0.01f * sc;
        if (sc > m) { den = den * __expf(m - sc) + 1.f; m = sc; }
        else den += __expf(sc - m);
    }
#pragma unroll
    for (int o = 32; o; o >>= 1) {
        float om = __shfl_xor(m, o, 64);
        float od = __shfl_xor(den, o, 64);
        float nm = fmaxf(m, om);
        den = den * __expf(m - nm) + od * __expf(om - nm);
        m = nm;
    }
    __shared__ float wm[4], wd[4];
    __shared__ float alpha_s[256];
    __shared__ int   src_s[256];
    if (lane == 0) { wm[wid] = m; wd[wid] = den; }
    __syncthreads();
    float M = fmaxf(fmaxf(wm[0], wm[1]), fmaxf(wm[2], wm[3]));
    float Dn = wd[0] * __expf(wm[0] - M) + wd[1] * __expf(wm[1] - M)
             + wd[2] * __expf(wm[2] - M) + wd[3] * __expf(wm[3] - M);
    float invD = 1.f / Dn;

    for (int c0 = beg; c0 < end; c0 += 256) {
        int e = c0 + tid;
        float al = 0.f; int sr = 0;
        if (e < end) {
            sr = srcs[e] - src_base;
            float sc = s[sr] + dd;
            sc = sc > 0.f ? sc : 0.01f * sc;
            al = __expf(sc - M) * invD;
        }
        __syncthreads();
        alpha_s[tid] = al; src_s[tid] = sr;
        __syncthreads();
        int cc = min(256, end - c0);
        for (int jj = 0; jj < cc; jj++) {
            const float* zr = z + (size_t)src_s[jj] * CD;
            float a = alpha_s[jj];
            float2 v = *(const float2*)(zr + tid * 2);
            bacc.x = fmaf(a, v.x, bacc.x);
            bacc.y = fmaf(a, v.y, bacc.y);
        }
    }
    *(float2*)(out + (size_t)b * CD + tid * 2) = bacc;
}

// ================= attention fuse for kn =================
__global__ __launch_bounds__(256) void fuse_kn(
    const float* __restrict__ kn, const float* __restrict__ kd,
    const float* __restrict__ ku, const float* __restrict__ Dm,
    const float* __restrict__ aw, const float* __restrict__ ab, float* __restrict__ out)
{
    const int i = blockIdx.x, tid = threadIdx.x;
    const int lane = tid & 63, wid = tid >> 6;
    const size_t ro = (size_t)i * CD + tid * 2;
    const int c = tid * 2;
    float2 vkn = *(const float2*)(kn + ro);
    float2 v1  = *(const float2*)(kd + ro);
    float2 v2  = *(const float2*)(ku + ro);
    float2 v3  = *(const float2*)(Dm + ro);
    float p1 = vkn.x*aw[c]      + vkn.y*aw[c+1]      + v1.x*aw[CD+c]      + v1.y*aw[CD+c+1];
    float p2 = vkn.x*aw[1024+c] + vkn.y*aw[1024+c+1] + v2.x*aw[1024+CD+c] + v2.y*aw[1024+CD+c+1];
    float p3 = vkn.x*aw[2048+c] + vkn.y*aw[2048+c+1] + v3.x*aw[2048+CD+c] + v3.y*aw[2048+CD+c+1];
#pragma unroll
    for (int o = 32; o; o >>= 1) {
        p1 += __shfl_xor(p1, o, 64); p2 += __shfl_xor(p2, o, 64); p3 += __shfl_xor(p3, o, 64);
    }
    __shared__ float r1[4], r2[4], r3[4];
    if (lane == 0) { r1[wid] = p1; r2[wid] = p2; r3[wid] = p3; }
    __syncthreads();
    float s1 = r1[0]+r1[1]+r1[2]+r1[3] + ab[0];
    float s2 = r2[0]+r2[1]+r2[2]+r2[3] + ab[1];
    float s3 = r3[0]+r3[1]+r3[2]+r3[3] + ab[2];
    float mm = fmaxf(s1, fmaxf(s2, s3));
    float e1 = __expf(s1-mm), e2 = __expf(s2-mm), e3 = __expf(s3-mm);
    float inv = 1.f / (e1 + e2 + e3);
    float w1 = e1*inv, w2 = e2*inv, w3 = e3*inv;
    float2 o_;
    o_.x = vkn.x + w1*v1.x + w2*v2.x + w3*v3.x;
    o_.y = vkn.y + w1*v1.y + w2*v2.y + w3*v3.y;
    *(float2*)(out + ro) = o_;
}

// ================= attention fuse for ex (optionally row-selected) =================
__global__ __launch_bounds__(256) void fuse_ex(
    const float* __restrict__ ex, const int* __restrict__ sel,
    const float* __restrict__ Bq, const float* __restrict__ Cq,
    const float* __restrict__ aw, const float* __restrict__ ab, float* __restrict__ out)
{
    const int i = blockIdx.x, tid = threadIdx.x;
    const int lane = tid & 63, wid = tid >> 6;
    const int exrow = sel ? sel[i] : i;
    const size_t eo = (size_t)exrow * CD + tid * 2;
    const size_t ro = (size_t)i * CD + tid * 2;
    const int c = tid * 2;
    float2 ve = *(const float2*)(ex + eo);
    float2 vb = *(const float2*)(Bq + ro);
    float2 vc = *(const float2*)(Cq + ro);
    const float* a3 = aw + 3 * 2 * CD;
    const float* a4 = aw + 4 * 2 * CD;
    float p1 = ve.x*a3[c] + ve.y*a3[c+1] + vb.x*a3[CD+c] + vb.y*a3[CD+c+1];
    float p2 = ve.x*a4[c] + ve.y*a4[c+1] + vc.x*a4[CD+c] + vc.y*a4[CD+c+1];
#pragma unroll
    for (int o = 32; o; o >>= 1) { p1 += __shfl_xor(p1, o, 64); p2 += __shfl_xor(p2, o, 64); }
    __shared__ float r1[4], r2[4];
    if (lane == 0) { r1[wid] = p1; r2[wid] = p2; }
    __syncthreads();
    float t1 = r1[0]+r1[1]+r1[2]+r1[3] + ab[3];
    float t2 = r2[0]+r2[1]+r2[2]+r2[3] + ab[4];
    float mm = fmaxf(t1, t2);
    float e1 = __expf(t1-mm), e2 = __expf(t2-mm);
    float inv = 1.f / (e1 + e2);
    float w1 = e1*inv, w2 = e2*inv;
    float2 o_;
    o_.x = ve.x + w1*vb.x + w2*vc.x;
    o_.y = ve.y + w1*vb.y + w2*vc.y;
    *(float2*)(out + ro) = o_;
}

// ================= final prediction =================
__global__ __launch_bounds__(256) void final_pred(
    const float* __restrict__ sP, const float* __restrict__ kP,
    const float* __restrict__ dP, const float* __restrict__ kD,
    const float* __restrict__ W3, const float* __restrict__ b3,
    const float* __restrict__ q_table, const int* __restrict__ qid,
    float* __restrict__ out)
{
    const int b = blockIdx.x;
    const int tid = threadIdx.x, lane = tid & 63, wid = tid >> 6;
    const float* sPr = sP + (size_t)b * CD;
    const float* dPr = dP + (size_t)b * CD;
    const float* qrow = q_table + (size_t)qid[b] * CD;
    const float bb = b3[0];
    float acc = 0.f, cnt = 0.f;
    for (int i = wid; i < CD; i += 4) {
        const float* kPr = kP + (size_t)i * CD;
        const float* kDr = kD + (size_t)i * CD;
        float o = 0.f;
#pragma unroll
        for (int p = 0; p < 8; p++) {
            int j = lane + (p << 6);
            float pv = sPr[j] + kPr[j];
            float dv = dPr[j] + kDr[j];
            float s1 = 1.f / (1.f + __expf(-pv));
            float s2 = 1.f / (1.f + __expf(-dv));
            o += (s1 - s2) * W3[j];
        }
#pragma unroll
        for (int ofs = 32; ofs; ofs >>= 1) o += __shfl_xor(o, ofs, 64);
        float ov = 1.f / (1.f + __expf(-(o + bb)));
        if (lane == 0) { float qv = qrow[i]; acc += ov * qv; cnt += qv; }
    }
    __shared__ float sa[4], sc[4];
    if (lane == 0) { sa[wid] = acc; sc[wid] = cnt; }
    __syncthreads();
    if (tid == 0) out[b] = (sa[0]+sa[1]+sa[2]+sa[3]) / (sc[0]+sc[1]+sc[2]+sc[3]);
}

// ================= host orchestration =================
extern "C" void kernel_launch(void* const* d_in, const int* in_sizes, int n_in,
                              void* d_out, int out_size, void* d_ws, size_t ws_size,
                              hipStream_t stream)
{
    const int*   user_id      = (const int*)d_in[0];
    const int*   question_id  = (const int*)d_in[1];
    const float* q_table      = (const float*)d_in[2];
    const int*   e_dir        = (const int*)d_in[3];
    const int*   e_und        = (const int*)d_in[4];
    const int*   e_ke         = (const int*)d_in[5];
    const int*   e_ek         = (const int*)d_in[6];
    const int*   e_ue         = (const int*)d_in[7];
    const int*   e_eu         = (const int*)d_in[8];
    const float* user_emb     = (const float*)d_in[9];
    const float* question_emb = (const float*)d_in[10];
    const float* concept_emb  = (const float*)d_in[11];
    const float* gat_W        = (const float*)d_in[12];
    const float* gat_a        = (const float*)d_in[13];
    const float* attn_w       = (const float*)d_in[14];
    const float* attn_b       = (const float*)d_in[15];
    const float* W1           = (const float*)d_in[16];
    const float* W2           = (const float*)d_in[17];
    const float* W3           = (const float*)d_in[18];
    const float* b3           = (const float*)d_in[19];
    float* out = (float*)d_out;

    char* wptr = (char*)d_ws;
    auto alloc = [&](size_t bytes) -> void* {
        void* p = (void*)wptr;
        wptr += (bytes + 255) & ~(size_t)255;
        return p;
    };

    // z zone: z2/z4 live in [0, 8000) and [8000, 16000); z5 reuses [0, 20000)
    // (l5 GEMM launches only after the l2 and l4 aggregates have consumed z2/z4).
    float* zone = (float*)alloc((size_t)UN * CD * 4);
    float* z2 = zone;
    float* z4 = zone + (size_t)QN * CD;
    float* z5 = zone;
    float* z0 = (float*)alloc((size_t)CD * CD * 4);
    float* z1 = (float*)alloc((size_t)CD * CD * 4);
    float* z3 = (float*)alloc((size_t)CD * CD * 4);

    // per-layer s (src scores) and dvals (dst scores)
    float* s0 = (float*)alloc((size_t)CD * 4);
    float* s1 = (float*)alloc((size_t)CD * 4);
    float* s2 = (float*)alloc((size_t)QN * 4);
    float* s3 = (float*)alloc((size_t)CD * 4);
    float* s4 = (float*)alloc((size_t)QN * 4);
    float* s5 = (float*)alloc((size_t)UN * 4);
    float* dv0 = (float*)alloc((size_t)CD * 4);
    float* dv1 = (float*)alloc((size_t)CD * 4);
    float* dv2 = (float*)alloc((size_t)CD * 4);
    float* dv3 = (float*)alloc((size_t)QN * 4);
    float* dv4 = (float*)alloc((size_t)UN * 4);
    float* dv5 = (float*)alloc((size_t)QN * 4);
    float* wa  = (float*)alloc((size_t)6 * CD * 4);

    float* kn1  = (float*)alloc((size_t)CD * CD * 4);
    float* ex1  = (float*)alloc((size_t)QN * CD * 4);
    float* stu1 = (float*)alloc((size_t)UN * CD * 4);
    float* kn2  = (float*)alloc((size_t)CD * CD * 4);
    float* kdir = (float*)alloc((size_t)CD * CD * 4);
    float* kund = (float*)alloc((size_t)CD * CD * 4);
    float* Dm   = (float*)alloc((size_t)CD * CD * 4);
    float* Bq   = (float*)alloc((size_t)QN * CD * 4);
    float* Cq   = (float*)alloc((size_t)QN * CD * 4);
    float* eb   = (float*)alloc((size_t)BATCHN * CD * 4);  // ex2 at question_id rows
    float* sb   = (float*)alloc((size_t)BATCHN * CD * 4);  // stu2 at user_id rows
    float* sP   = (float*)alloc((size_t)BATCHN * CD * 4);
    float* dP   = (float*)alloc((size_t)BATCHN * CD * 4);
    float* kP   = (float*)alloc((size_t)CD * CD * 4);
    float* kD   = (float*)alloc((size_t)CD * CD * 4);

    static const int g_ne[6]   = {4096, 8192, 40000, 40000, 100000, 100000};
    static const int g_nd[6]   = {512, 512, 512, QN, UN, QN};
    static const int g_base[6] = {0, 0, QN, 0, QN, 0};
    const int* g_edges[6] = {e_dir, e_und, e_ke, e_ek, e_ue, e_eu};

    int* off[6]; int* srcs[6];
    for (int g = 0; g < 6; g++) {
        off[g]  = (int*)alloc((size_t)(g_nd[g] + 1) * 4);
        srcs[g] = (int*)alloc((size_t)g_ne[g] * 4);
    }

    CsrJobs jobs;
    for (int g = 0; g < 6; g++) {
        jobs.j[g].src = g_edges[g];
        jobs.j[g].dst = g_edges[g] + g_ne[g];
        jobs.j[g].n_edges = g_ne[g];
        jobs.j[g].n_dst = g_nd[g];
        jobs.j[g].dst_base = g_base[g];
        jobs.j[g].off = off[g];
        jobs.j[g].srcs = srcs[g];
    }
    build_csr<<<6, 1024, 0, stream>>>(jobs);

    auto gemm = [&](const float* A, int n, const float* B0, float* C0,
                    const float* B1, float* C1) {
        dim3 g((n + GBM - 1) / GBM, B1 ? 8 : 4);
        gemm_f32<<<g, 256, 0, stream>>>(A, n, B0, C0, B1, C1);
    };
    auto dots = [&](const float* H, const int* sel, const float* v, float* o, int n) {
        dot_rows<<<(n + 3) / 4, 256, 0, stream>>>(H, sel, v, o, n);
    };
    auto agg = [&](int g, int src_base, const int* sel, const float* z, const float* s,
                   const float* dv, const float* base, float* o, int nblk) {
        gat_aggregate<<<nblk, 256, 0, stream>>>(off[g], srcs[g], src_base, sel,
                                                z, s, dv, base, o);
    };

    // fusion: selq/selu null => full dst sets (fusion 1); else 128-row selections.
    auto run_fusion = [&](int f, const float* kn, const float* ex, const float* stu,
                          const int* selq, const int* selu, int nd3, int nd4, int nd5,
                          float* kn_o, float* ex_o, float* stu_o) {
        const float* Wf  = gat_W  + (size_t)f * 6 * CDCD;
        const float* af  = gat_a  + (size_t)f * 6 * 2 * CD;
        const float* awf = attn_w + (size_t)f * 5 * 2 * CD;
        const float* abf = attn_b + (size_t)f * 5;

        wa_gemv6<<<dim3(128, 6), 256, 0, stream>>>(Wf, af, wa);

        // l0 + l1 (A = kn, dual B)
        gemm(kn, CD, Wf + 0 * CDCD, z0, Wf + 1 * CDCD, z1);
        dots(z0, nullptr, af + 0 * 2 * CD, s0, CD);
        dots(z1, nullptr, af + 1 * 2 * CD, s1, CD);
        dots(kn, nullptr, wa + 0 * CD, dv0, CD);
        dots(kn, nullptr, wa + 1 * CD, dv1, CD);
        agg(0, 0, nullptr, z0, s0, dv0, nullptr, kdir, CD);
        agg(1, 0, nullptr, z1, s1, dv1, nullptr, kund, CD);

        // l2 + l4 (A = ex, dual B)
        gemm(ex, QN, Wf + 2 * CDCD, z2, Wf + 4 * CDCD, z4);
        dots(z2, nullptr, af + 2 * 2 * CD, s2, QN);
        dots(kn, nullptr, wa + 2 * CD, dv2, CD);
        agg(2, 0, nullptr, z2, s2, dv2, nullptr, Dm, CD);

        // l3 (A = kn; sources of ek are the concept rows of ekg)
        gemm(kn, CD, Wf + 3 * CDCD, z3, nullptr, nullptr);
        dots(z3, nullptr, af + 3 * 2 * CD, s3, CD);
        dots(ex, selq, wa + 3 * CD, dv3, nd3);
        agg(3, QN, selq, z3, s3, dv3, nullptr, Bq, nd3);

        // l4 (z4 already computed; sources of ue are the ex rows of eug)
        dots(z4, nullptr, af + 4 * 2 * CD, s4, QN);
        dots(stu, selu, wa + 4 * CD, dv4, nd4);
        agg(4, 0, selu, z4, s4, dv4, stu, stu_o, nd4);

        // l5 (A = stu; z5 overwrites zone AFTER l2/l4 aggregates consumed it)
        gemm(stu, UN, Wf + 5 * CDCD, z5, nullptr, nullptr);
        dots(z5, nullptr, af + 5 * 2 * CD, s5, UN);
        dots(ex, selq, wa + 5 * CD, dv5, nd5);
        agg(5, QN, selq, z5, s5, dv5, nullptr, Cq, nd5);

        fuse_kn<<<CD, 256, 0, stream>>>(kn, kdir, kund, Dm, awf, abf, kn_o);
        fuse_ex<<<nd3, 256, 0, stream>>>(ex, selq, Bq, Cq, awf, abf, ex_o);
    };

    run_fusion(0, concept_emb, question_emb, user_emb,
               nullptr, nullptr, QN, UN, QN, kn1, ex1, stu1);
    run_fusion(1, kn1, ex1, stu1,
               question_id, user_id, BATCHN, BATCHN, BATCHN, kn2, eb, sb);

    // prediction head
    gemm(sb, BATCHN, W1, sP, nullptr, nullptr);
    gemm(eb, BATCHN, W2, dP, nullptr, nullptr);
    gemm(kn2, CD, W1 + (size_t)CDCD, kP, W2 + (size_t)CDCD, kD);
    final_pred<<<BATCHN, 256, 0, stream>>>(sP, kP, dP, kD, W3, b3, q_table, question_id, out);
}

// Round 3
// 1659.041 us; speedup vs baseline: 1.1708x; 1.1708x over previous
//
#include <hip/hip_runtime.h>
#include <math.h>

#define CD 512
#define CDCD (CD * CD)
#define QN 8000
#define UN 20000
#define BATCHN 128

// ================= GEMM: C[n x 512] = A[n x 512] @ B[512 x 512] =================
// Optional second (B1,C1) pair sharing the same A (launch grid.y = 8 instead of 4).
#define GBM 128
#define GBN 128
#define GBK 32

__global__ __launch_bounds__(256) void gemm_f32(
    const float* __restrict__ A, int n,
    const float* __restrict__ B0, float* __restrict__ C0,
    const float* __restrict__ B1, float* __restrict__ C1)
{
    __shared__ __align__(16) float As[GBK][GBM];
    __shared__ __align__(16) float Bs[GBK][GBN];
    const int which = blockIdx.y >> 2;
    const float* __restrict__ B = which ? B1 : B0;
    float* __restrict__ C = which ? C1 : C0;
    const int bm = blockIdx.x * GBM, bn = (blockIdx.y & 3) * GBN;
    const int tid = threadIdx.x;
    const int tx = tid & 15, ty = tid >> 4;
    const int arow = tid >> 1, akq = (tid & 1) * 16;   // each thread: 16 A floats
    const int bkr = tid >> 4, bcol = (tid & 15) * 8;   // rows bkr, bkr+16; 8 cols
    const int gr = bm + arow;
    const bool aok = (gr < n);
    const float* Arow = A + (size_t)(aok ? gr : 0) * CD;

    float acc[8][8];
#pragma unroll
    for (int i = 0; i < 8; i++)
#pragma unroll
        for (int j = 0; j < 8; j++) acc[i][j] = 0.f;

    for (int k0 = 0; k0 < CD; k0 += GBK) {
        float4 av[4];
#pragma unroll
        for (int c = 0; c < 4; c++) av[c] = make_float4(0.f, 0.f, 0.f, 0.f);
        if (aok) {
#pragma unroll
            for (int c = 0; c < 4; c++)
                av[c] = *(const float4*)(Arow + k0 + akq + c * 4);
        }
        float4 bv[4];
        bv[0] = *(const float4*)(B + (size_t)(k0 + bkr) * CD + bn + bcol);
        bv[1] = *(const float4*)(B + (size_t)(k0 + bkr) * CD + bn + bcol + 4);
        bv[2] = *(const float4*)(B + (size_t)(k0 + bkr + 16) * CD + bn + bcol);
        bv[3] = *(const float4*)(B + (size_t)(k0 + bkr + 16) * CD + bn + bcol + 4);
        __syncthreads();
#pragma unroll
        for (int c = 0; c < 4; c++) {
            As[akq + c * 4 + 0][arow] = av[c].x;
            As[akq + c * 4 + 1][arow] = av[c].y;
            As[akq + c * 4 + 2][arow] = av[c].z;
            As[akq + c * 4 + 3][arow] = av[c].w;
        }
        *(float4*)&Bs[bkr][bcol]          = bv[0];
        *(float4*)&Bs[bkr][bcol + 4]      = bv[1];
        *(float4*)&Bs[bkr + 16][bcol]     = bv[2];
        *(float4*)&Bs[bkr + 16][bcol + 4] = bv[3];
        __syncthreads();
#pragma unroll
        for (int kk = 0; kk < GBK; kk++) {
            float a0[8], b0[8];
            *(float4*)&a0[0] = *(const float4*)&As[kk][ty * 8];
            *(float4*)&a0[4] = *(const float4*)&As[kk][ty * 8 + 4];
            *(float4*)&b0[0] = *(const float4*)&Bs[kk][tx * 8];
            *(float4*)&b0[4] = *(const float4*)&Bs[kk][tx * 8 + 4];
#pragma unroll
            for (int i = 0; i < 8; i++)
#pragma unroll
                for (int j = 0; j < 8; j++)
                    acc[i][j] = fmaf(a0[i], b0[j], acc[i][j]);
        }
    }
    const int orow = bm + ty * 8, ocol = bn + tx * 8;
#pragma unroll
    for (int i = 0; i < 8; i++) {
        int r = orow + i;
        if (r < n) {
            *(float4*)(C + (size_t)r * CD + ocol) =
                make_float4(acc[i][0], acc[i][1], acc[i][2], acc[i][3]);
            *(float4*)(C + (size_t)r * CD + ocol + 4) =
                make_float4(acc[i][4], acc[i][5], acc[i][6], acc[i][7]);
        }
    }
}

// ========== dot_rows: out[r] = H[sel?sel[r]:r] . v   (one wave per row) ==========
__global__ __launch_bounds__(256) void dot_rows(
    const float* __restrict__ H, const int* __restrict__ sel,
    const float* __restrict__ v, float* __restrict__ out, int n)
{
    const int lane = threadIdx.x & 63;
    const int r = blockIdx.x * 4 + (threadIdx.x >> 6);
    if (r >= n) return;
    const int row = sel ? sel[r] : r;
    const float* h = H + (size_t)row * CD;
    float4 a0 = *(const float4*)(h + lane * 8);
    float4 a1 = *(const float4*)(h + lane * 8 + 4);
    float4 b0 = *(const float4*)(v + lane * 8);
    float4 b1 = *(const float4*)(v + lane * 8 + 4);
    float sv = a0.x * b0.x + a0.y * b0.y + a0.z * b0.z + a0.w * b0.w
             + a1.x * b1.x + a1.y * b1.y + a1.z * b1.z + a1.w * b1.w;
#pragma unroll
    for (int o = 32; o; o >>= 1) sv += __shfl_xor(sv, o, 64);
    if (lane == 0) out[r] = sv;
}

// ========== wa_gemv6: wa[l][k] = sum_j W[l][k][j] * a[l][CD + j], l = 0..5 ==========
__global__ __launch_bounds__(256) void wa_gemv6(
    const float* __restrict__ W6, const float* __restrict__ a6, float* __restrict__ wa)
{
    const int layer = blockIdx.y;
    const int lane = threadIdx.x & 63;
    const int r = blockIdx.x * 4 + (threadIdx.x >> 6);   // 0..511 (grid.x = 128)
    const float* Wr = W6 + (size_t)layer * CDCD + (size_t)r * CD;
    const float* ah = a6 + layer * 2 * CD + CD;
    float4 a0 = *(const float4*)(Wr + lane * 8);
    float4 a1 = *(const float4*)(Wr + lane * 8 + 4);
    float4 b0 = *(const float4*)(ah + lane * 8);
    float4 b1 = *(const float4*)(ah + lane * 8 + 4);
    float sv = a0.x * b0.x + a0.y * b0.y + a0.z * b0.z + a0.w * b0.w
             + a1.x * b1.x + a1.y * b1.y + a1.z * b1.z + a1.w * b1.w;
#pragma unroll
    for (int o = 32; o; o >>= 1) sv += __shfl_xor(sv, o, 64);
    if (lane == 0) wa[layer * CD + r] = sv;
}

// ================= CSR build (one block per graph) =================
struct CsrJob {
    const int* src; const int* dst;
    int n_edges; int n_dst; int dst_base;
    int* off; int* srcs;
};
struct CsrJobs { CsrJob j[6]; };

__global__ __launch_bounds__(1024) void build_csr(CsrJobs jobs)
{
    __shared__ int cnt[UN];
    __shared__ int wsum[16];
    CsrJob jb = jobs.j[blockIdx.x];
    const int tid = threadIdx.x;
    const int lane = tid & 63, wid = tid >> 6;
    const int n = jb.n_dst;

    for (int i = tid; i < n; i += 1024) cnt[i] = 0;
    __syncthreads();
    for (int e = tid; e < jb.n_edges; e += 1024)
        atomicAdd(&cnt[jb.dst[e] - jb.dst_base], 1);
    __syncthreads();

    int running = 0;
    for (int base = 0; base < n; base += 1024) {
        int idx = base + tid;
        int v0 = (idx < n) ? cnt[idx] : 0;
        int v = v0;
#pragma unroll
        for (int dlt = 1; dlt < 64; dlt <<= 1) {
            int t = __shfl_up(v, dlt, 64);
            if (lane >= dlt) v += t;
        }
        if (lane == 63) wsum[wid] = v;
        __syncthreads();
        if (wid == 0) {
            int wv = (lane < 16) ? wsum[lane] : 0;
#pragma unroll
            for (int dlt = 1; dlt < 16; dlt <<= 1) {
                int t = __shfl_up(wv, dlt, 64);
                if (lane >= dlt) wv += t;
            }
            if (lane < 16) wsum[lane] = wv;
        }
        __syncthreads();
        int wprefix = (wid > 0) ? wsum[wid - 1] : 0;
        int chunk_total = wsum[15];
        int excl = running + wprefix + (v - v0);
        if (idx < n) { jb.off[idx] = excl; cnt[idx] = excl; }
        running += chunk_total;
        __syncthreads();
    }
    if (tid == 0) jb.off[n] = running;
    // scatter (cnt[] now holds running cursors at exclusive offsets)
    for (int e = tid; e < jb.n_edges; e += 1024) {
        int dl = jb.dst[e] - jb.dst_base;
        int pos = atomicAdd(&cnt[dl], 1);
        jb.srcs[pos] = jb.src[e];
    }
}

// ================= GAT aggregate: one block per (possibly selected) dst node ======
__global__ __launch_bounds__(256) void gat_aggregate(
    const int* __restrict__ off, const int* __restrict__ srcs, int src_base,
    const int* __restrict__ sel,
    const float* __restrict__ z, const float* __restrict__ s,
    const float* __restrict__ dvals,
    const float* __restrict__ base, float* __restrict__ out)
{
    const int b = blockIdx.x;
    const int node = sel ? sel[b] : b;
    const int tid = threadIdx.x;
    const int lane = tid & 63, wid = tid >> 6;
    const int beg = off[node], end = off[node + 1];

    float2 bacc = base ? *(const float2*)(base + (size_t)node * CD + tid * 2)
                       : make_float2(0.f, 0.f);
    if (beg == end) {
        *(float2*)(out + (size_t)b * CD + tid * 2) = bacc;
        return;
    }
    const float dd = dvals[b];

    float m = -1e30f, den = 0.f;
    for (int e = beg + tid; e < end; e += 256) {
        float sc = s[srcs[e] - src_base] + dd;
        sc = sc > 0.f ? sc : 0.01f * sc;
        if (sc > m) { den = den * __expf(m - sc) + 1.f; m = sc; }
        else den += __expf(sc - m);
    }
#pragma unroll
    for (int o = 32; o; o >>= 1) {
        float om = __shfl_xor(m, o, 64);
        float od = __shfl_xor(den, o, 64);
        float nm = fmaxf(m, om);
        den = den * __expf(m - nm) + od * __expf(om - nm);
        m = nm;
    }
    __shared__ float wm[4], wd[4];
    __shared__ float alpha_s[256];
    __shared__ int   src_s[256];
    if (lane == 0) { wm[wid] = m; wd[wid] = den; }
    __syncthreads();
    float M = fmaxf(fmaxf(wm[0], wm[1]), fmaxf(wm[2], wm[3]));
    float Dn = wd[0] * __expf(wm[0] - M) + wd[1] * __expf(wm[1] - M)
             + wd[2] * __expf(wm[2] - M) + wd[3] * __expf(wm[3] - M);
    float invD = 1.f / Dn;

    for (int c0 = beg; c0 < end; c0 += 256) {
        int e = c0 + tid;
        float al = 0.f; int sr = 0;
        if (e < end) {
            sr = srcs[e] - src_base;
            float sc = s[sr] + dd;
            sc = sc > 0.f ? sc : 0.01f * sc;
            al = __expf(sc - M) * invD;
        }
        __syncthreads();
        alpha_s[tid] = al; src_s[tid] = sr;
        __syncthreads();
        int cc = min(256, end - c0);
        for (int jj = 0; jj < cc; jj++) {
            const float* zr = z + (size_t)src_s[jj] * CD;
            float a = alpha_s[jj];
            float2 v = *(const float2*)(zr + tid * 2);
            bacc.x = fmaf(a, v.x, bacc.x);
            bacc.y = fmaf(a, v.y, bacc.y);
        }
    }
    *(float2*)(out + (size_t)b * CD + tid * 2) = bacc;
}

// ================= attention fuse for kn =================
__global__ __launch_bounds__(256) void fuse_kn(
    const float* __restrict__ kn, const float* __restrict__ kd,
    const float* __restrict__ ku, const float* __restrict__ Dm,
    const float* __restrict__ aw, const float* __restrict__ ab, float* __restrict__ out)
{
    const int i = blockIdx.x, tid = threadIdx.x;
    const int lane = tid & 63, wid = tid >> 6;
    const size_t ro = (size_t)i * CD + tid * 2;
    const int c = tid * 2;
    float2 vkn = *(const float2*)(kn + ro);
    float2 v1  = *(const float2*)(kd + ro);
    float2 v2  = *(const float2*)(ku + ro);
    float2 v3  = *(const float2*)(Dm + ro);
    float p1 = vkn.x*aw[c]      + vkn.y*aw[c+1]      + v1.x*aw[CD+c]      + v1.y*aw[CD+c+1];
    float p2 = vkn.x*aw[1024+c] + vkn.y*aw[1024+c+1] + v2.x*aw[1024+CD+c] + v2.y*aw[1024+CD+c+1];
    float p3 = vkn.x*aw[2048+c] + vkn.y*aw[2048+c+1] + v3.x*aw[2048+CD+c] + v3.y*aw[2048+CD+c+1];
#pragma unroll
    for (int o = 32; o; o >>= 1) {
        p1 += __shfl_xor(p1, o, 64); p2 += __shfl_xor(p2, o, 64); p3 += __shfl_xor(p3, o, 64);
    }
    __shared__ float r1[4], r2[4], r3[4];
    if (lane == 0) { r1[wid] = p1; r2[wid] = p2; r3[wid] = p3; }
    __syncthreads();
    float s1 = r1[0]+r1[1]+r1[2]+r1[3] + ab[0];
    float s2 = r2[0]+r2[1]+r2[2]+r2[3] + ab[1];
    float s3 = r3[0]+r3[1]+r3[2]+r3[3] + ab[2];
    float mm = fmaxf(s1, fmaxf(s2, s3));
    float e1 = __expf(s1-mm), e2 = __expf(s2-mm), e3 = __expf(s3-mm);
    float inv = 1.f / (e1 + e2 + e3);
    float w1 = e1*inv, w2 = e2*inv, w3 = e3*inv;
    float2 o_;
    o_.x = vkn.x + w1*v1.x + w2*v2.x + w3*v3.x;
    o_.y = vkn.y + w1*v1.y + w2*v2.y + w3*v3.y;
    *(float2*)(out + ro) = o_;
}

// ================= attention fuse for ex (optionally row-selected) =================
__global__ __launch_bounds__(256) void fuse_ex(
    const float* __restrict__ ex, const int* __restrict__ sel,
    const float* __restrict__ Bq, const float* __restrict__ Cq,
    const float* __restrict__ aw, const float* __restrict__ ab, float* __restrict__ out)
{
    const int i = blockIdx.x, tid = threadIdx.x;
    const int lane = tid & 63, wid = tid >> 6;
    const int exrow = sel ? sel[i] : i;
    const size_t eo = (size_t)exrow * CD + tid * 2;
    const size_t ro = (size_t)i * CD + tid * 2;
    const int c = tid * 2;
    float2 ve = *(const float2*)(ex + eo);
    float2 vb = *(const float2*)(Bq + ro);
    float2 vc = *(const float2*)(Cq + ro);
    const float* a3 = aw + 3 * 2 * CD;
    const float* a4 = aw + 4 * 2 * CD;
    float p1 = ve.x*a3[c] + ve.y*a3[c+1] + vb.x*a3[CD+c] + vb.y*a3[CD+c+1];
    float p2 = ve.x*a4[c] + ve.y*a4[c+1] + vc.x*a4[CD+c] + vc.y*a4[CD+c+1];
#pragma unroll
    for (int o = 32; o; o >>= 1) { p1 += __shfl_xor(p1, o, 64); p2 += __shfl_xor(p2, o, 64); }
    __shared__ float r1[4], r2[4];
    if (lane == 0) { r1[wid] = p1; r2[wid] = p2; }
    __syncthreads();
    float t1 = r1[0]+r1[1]+r1[2]+r1[3] + ab[3];
    float t2 = r2[0]+r2[1]+r2[2]+r2[3] + ab[4];
    float mm = fmaxf(t1, t2);
    float e1 = __expf(t1-mm), e2 = __expf(t2-mm);
    float inv = 1.f / (e1 + e2);
    float w1 = e1*inv, w2 = e2*inv;
    float2 o_;
    o_.x = ve.x + w1*vb.x + w2*vc.x;
    o_.y = ve.y + w1*vb.y + w2*vc.y;
    *(float2*)(out + ro) = o_;
}

// ===== final prediction, q_table-sparse: only ~5 of 512 concepts have qb!=0 =====
__global__ __launch_bounds__(256) void final_pred(
    const float* __restrict__ sP, const float* __restrict__ kP,
    const float* __restrict__ dP, const float* __restrict__ kD,
    const float* __restrict__ W3, const float* __restrict__ b3,
    const float* __restrict__ q_table, const int* __restrict__ qid,
    float* __restrict__ out)
{
    const int b = blockIdx.x;
    const int tid = threadIdx.x, lane = tid & 63, wid = tid >> 6;
    __shared__ int   sidx[CD];
    __shared__ float sqv[CD];
    __shared__ int   snn;
    __shared__ float scnt[4], sacc[4];
    if (tid == 0) snn = 0;
    __syncthreads();
    const float* qrow = q_table + (size_t)qid[b] * CD;
    float cnt = 0.f;
    for (int i = tid; i < CD; i += 256) {
        float qv = qrow[i];
        if (qv != 0.f) {
            int p = atomicAdd(&snn, 1);
            sidx[p] = i; sqv[p] = qv;
            cnt += qv;
        }
    }
#pragma unroll
    for (int o = 32; o; o >>= 1) cnt += __shfl_xor(cnt, o, 64);
    if (lane == 0) scnt[wid] = cnt;
    __syncthreads();
    const int nn = snn;
    const float bb = b3[0];
    const float* sPr = sP + (size_t)b * CD;
    const float* dPr = dP + (size_t)b * CD;
    float acc = 0.f;
    for (int t = wid; t < nn; t += 4) {
        const int i = sidx[t];
        const float* kPr = kP + (size_t)i * CD;
        const float* kDr = kD + (size_t)i * CD;
        float o = 0.f;
#pragma unroll
        for (int p = 0; p < 8; p++) {
            int j = lane + (p << 6);
            float pv = sPr[j] + kPr[j];
            float dv = dPr[j] + kDr[j];
            float s1 = 1.f / (1.f + __expf(-pv));
            float s2 = 1.f / (1.f + __expf(-dv));
            o += (s1 - s2) * W3[j];
        }
#pragma unroll
        for (int ofs = 32; ofs; ofs >>= 1) o += __shfl_xor(o, ofs, 64);
        if (lane == 0) acc += sqv[t] / (1.f + __expf(-(o + bb)));
    }
    if (lane == 0) sacc[wid] = acc;
    __syncthreads();
    if (tid == 0)
        out[b] = (sacc[0] + sacc[1] + sacc[2] + sacc[3])
               / (scnt[0] + scnt[1] + scnt[2] + scnt[3]);
}

// ================= host orchestration =================
extern "C" void kernel_launch(void* const* d_in, const int* in_sizes, int n_in,
                              void* d_out, int out_size, void* d_ws, size_t ws_size,
                              hipStream_t stream)
{
    const int*   user_id      = (const int*)d_in[0];
    const int*   question_id  = (const int*)d_in[1];
    const float* q_table      = (const float*)d_in[2];
    const int*   e_dir        = (const int*)d_in[3];
    const int*   e_und        = (const int*)d_in[4];
    const int*   e_ke         = (const int*)d_in[5];
    const int*   e_ek         = (const int*)d_in[6];
    const int*   e_ue         = (const int*)d_in[7];
    const int*   e_eu         = (const int*)d_in[8];
    const float* user_emb     = (const float*)d_in[9];
    const float* question_emb = (const float*)d_in[10];
    const float* concept_emb  = (const float*)d_in[11];
    const float* gat_W        = (const float*)d_in[12];
    const float* gat_a        = (const float*)d_in[13];
    const float* attn_w       = (const float*)d_in[14];
    const float* attn_b       = (const float*)d_in[15];
    const float* W1           = (const float*)d_in[16];
    const float* W2           = (const float*)d_in[17];
    const float* W3           = (const float*)d_in[18];
    const float* b3           = (const float*)d_in[19];
    float* out = (float*)d_out;

    char* wptr = (char*)d_ws;
    auto alloc = [&](size_t bytes) -> void* {
        void* p = (void*)wptr;
        wptr += (bytes + 255) & ~(size_t)255;
        return p;
    };

    // z zone: z2/z4 live in [0, 8000) and [8000, 16000); z5 reuses [0, 20000)
    float* zone = (float*)alloc((size_t)UN * CD * 4);
    float* z2 = zone;
    float* z4 = zone + (size_t)QN * CD;
    float* z5 = zone;
    float* z0 = (float*)alloc((size_t)CD * CD * 4);
    float* z1 = (float*)alloc((size_t)CD * CD * 4);
    float* z3 = (float*)alloc((size_t)CD * CD * 4);

    float* s0 = (float*)alloc((size_t)CD * 4);
    float* s1 = (float*)alloc((size_t)CD * 4);
    float* s2 = (float*)alloc((size_t)QN * 4);
    float* s3 = (float*)alloc((size_t)CD * 4);
    float* s4 = (float*)alloc((size_t)QN * 4);
    float* s5 = (float*)alloc((size_t)UN * 4);
    float* dv0 = (float*)alloc((size_t)CD * 4);
    float* dv1 = (float*)alloc((size_t)CD * 4);
    float* dv2 = (float*)alloc((size_t)CD * 4);
    float* dv3 = (float*)alloc((size_t)QN * 4);
    float* dv4 = (float*)alloc((size_t)UN * 4);
    float* dv5 = (float*)alloc((size_t)QN * 4);
    float* wa  = (float*)alloc((size_t)6 * CD * 4);

    float* kn1  = (float*)alloc((size_t)CD * CD * 4);
    float* ex1  = (float*)alloc((size_t)QN * CD * 4);
    float* stu1 = (float*)alloc((size_t)UN * CD * 4);
    float* kn2  = (float*)alloc((size_t)CD * CD * 4);
    float* kdir = (float*)alloc((size_t)CD * CD * 4);
    float* kund = (float*)alloc((size_t)CD * CD * 4);
    float* Dm   = (float*)alloc((size_t)CD * CD * 4);
    float* Bq   = (float*)alloc((size_t)QN * CD * 4);
    float* Cq   = (float*)alloc((size_t)QN * CD * 4);
    float* eb   = (float*)alloc((size_t)BATCHN * CD * 4);
    float* sb   = (float*)alloc((size_t)BATCHN * CD * 4);
    float* sP   = (float*)alloc((size_t)BATCHN * CD * 4);
    float* dP   = (float*)alloc((size_t)BATCHN * CD * 4);
    float* kP   = (float*)alloc((size_t)CD * CD * 4);
    float* kD   = (float*)alloc((size_t)CD * CD * 4);

    static const int g_ne[6]   = {4096, 8192, 40000, 40000, 100000, 100000};
    static const int g_nd[6]   = {512, 512, 512, QN, UN, QN};
    static const int g_base[6] = {0, 0, QN, 0, QN, 0};
    const int* g_edges[6] = {e_dir, e_und, e_ke, e_ek, e_ue, e_eu};

    int* off[6]; int* srcs[6];
    for (int g = 0; g < 6; g++) {
        off[g]  = (int*)alloc((size_t)(g_nd[g] + 1) * 4);
        srcs[g] = (int*)alloc((size_t)g_ne[g] * 4);
    }

    CsrJobs jobs;
    for (int g = 0; g < 6; g++) {
        jobs.j[g].src = g_edges[g];
        jobs.j[g].dst = g_edges[g] + g_ne[g];
        jobs.j[g].n_edges = g_ne[g];
        jobs.j[g].n_dst = g_nd[g];
        jobs.j[g].dst_base = g_base[g];
        jobs.j[g].off = off[g];
        jobs.j[g].srcs = srcs[g];
    }
    build_csr<<<6, 1024, 0, stream>>>(jobs);

    auto gemm = [&](const float* A, int n, const float* B0, float* C0,
                    const float* B1, float* C1) {
        dim3 g((n + GBM - 1) / GBM, B1 ? 8 : 4);
        gemm_f32<<<g, 256, 0, stream>>>(A, n, B0, C0, B1, C1);
    };
    auto dots = [&](const float* H, const int* sel, const float* v, float* o, int n) {
        dot_rows<<<(n + 3) / 4, 256, 0, stream>>>(H, sel, v, o, n);
    };
    auto agg = [&](int g, int src_base, const int* sel, const float* z, const float* s,
                   const float* dv, const float* base, float* o, int nblk) {
        gat_aggregate<<<nblk, 256, 0, stream>>>(off[g], srcs[g], src_base, sel,
                                                z, s, dv, base, o);
    };

    auto run_fusion = [&](int f, const float* kn, const float* ex, const float* stu,
                          const int* selq, const int* selu, int nd3, int nd4, int nd5,
                          float* kn_o, float* ex_o, float* stu_o) {
        const float* Wf  = gat_W  + (size_t)f * 6 * CDCD;
        const float* af  = gat_a  + (size_t)f * 6 * 2 * CD;
        const float* awf = attn_w + (size_t)f * 5 * 2 * CD;
        const float* abf = attn_b + (size_t)f * 5;

        wa_gemv6<<<dim3(128, 6), 256, 0, stream>>>(Wf, af, wa);

        // l0 + l1 (A = kn, dual B)
        gemm(kn, CD, Wf + 0 * CDCD, z0, Wf + 1 * CDCD, z1);
        dots(z0, nullptr, af + 0 * 2 * CD, s0, CD);
        dots(z1, nullptr, af + 1 * 2 * CD, s1, CD);
        dots(kn, nullptr, wa + 0 * CD, dv0, CD);
        dots(kn, nullptr, wa + 1 * CD, dv1, CD);
        agg(0, 0, nullptr, z0, s0, dv0, nullptr, kdir, CD);
        agg(1, 0, nullptr, z1, s1, dv1, nullptr, kund, CD);

        // l2 + l4 (A = ex, dual B)
        gemm(ex, QN, Wf + 2 * CDCD, z2, Wf + 4 * CDCD, z4);
        dots(z2, nullptr, af + 2 * 2 * CD, s2, QN);
        dots(kn, nullptr, wa + 2 * CD, dv2, CD);
        agg(2, 0, nullptr, z2, s2, dv2, nullptr, Dm, CD);

        // l3 (A = kn; sources of ek are the concept rows of ekg)
        gemm(kn, CD, Wf + 3 * CDCD, z3, nullptr, nullptr);
        dots(z3, nullptr, af + 3 * 2 * CD, s3, CD);
        dots(ex, selq, wa + 3 * CD, dv3, nd3);
        agg(3, QN, selq, z3, s3, dv3, nullptr, Bq, nd3);

        // l4 (z4 already computed; sources of ue are the ex rows of eug)
        dots(z4, nullptr, af + 4 * 2 * CD, s4, QN);
        dots(stu, selu, wa + 4 * CD, dv4, nd4);
        agg(4, 0, selu, z4, s4, dv4, stu, stu_o, nd4);

        // l5 (A = stu; z5 overwrites zone AFTER l2/l4 aggregates consumed it)
        gemm(stu, UN, Wf + 5 * CDCD, z5, nullptr, nullptr);
        dots(z5, nullptr, af + 5 * 2 * CD, s5, UN);
        dots(ex, selq, wa + 5 * CD, dv5, nd5);
        agg(5, QN, selq, z5, s5, dv5, nullptr, Cq, nd5);

        fuse_kn<<<CD, 256, 0, stream>>>(kn, kdir, kund, Dm, awf, abf, kn_o);
        fuse_ex<<<nd3, 256, 0, stream>>>(ex, selq, Bq, Cq, awf, abf, ex_o);
    };

    run_fusion(0, concept_emb, question_emb, user_emb,
               nullptr, nullptr, QN, UN, QN, kn1, ex1, stu1);
    run_fusion(1, kn1, ex1, stu1,
               question_id, user_id, BATCHN, BATCHN, BATCHN, kn2, eb, sb);

    // prediction head
    gemm(sb, BATCHN, W1, sP, nullptr, nullptr);
    gemm(eb, BATCHN, W2, dP, nullptr, nullptr);
    gemm(kn2, CD, W1 + (size_t)CDCD, kP, W2 + (size_t)CDCD, kD);
    final_pred<<<BATCHN, 256, 0, stream>>>(sP, kP, dP, kD, W3, b3, q_table, question_id, out);
}

// Round 4
// 1458.615 us; speedup vs baseline: 1.3317x; 1.1374x over previous
//
#include <hip/hip_runtime.h>
#include <math.h>

#define CD 512
#define CDCD (CD * CD)
#define QN 8000
#define UN 20000
#define BATCHN 128

// ================= GEMM: C[n x 512] = A[n x 512] @ B[512 x 512] =================
// Optional second (B1,C1) pair sharing the same A (launch grid.y = 8 instead of 4).
#define GBM 128
#define GBN 128
#define GBK 32

__global__ __launch_bounds__(256) void gemm_f32(
    const float* __restrict__ A, int n,
    const float* __restrict__ B0, float* __restrict__ C0,
    const float* __restrict__ B1, float* __restrict__ C1)
{
    __shared__ __align__(16) float As[GBK][GBM];
    __shared__ __align__(16) float Bs[GBK][GBN];
    const int which = blockIdx.y >> 2;
    const float* __restrict__ B = which ? B1 : B0;
    float* __restrict__ C = which ? C1 : C0;
    const int bm = blockIdx.x * GBM, bn = (blockIdx.y & 3) * GBN;
    const int tid = threadIdx.x;
    const int tx = tid & 15, ty = tid >> 4;
    const int arow = tid >> 1, akq = (tid & 1) * 16;
    const int bkr = tid >> 4, bcol = (tid & 15) * 8;
    const int gr = bm + arow;
    const bool aok = (gr < n);
    const float* Arow = A + (size_t)(aok ? gr : 0) * CD;

    float acc[8][8];
#pragma unroll
    for (int i = 0; i < 8; i++)
#pragma unroll
        for (int j = 0; j < 8; j++) acc[i][j] = 0.f;

    for (int k0 = 0; k0 < CD; k0 += GBK) {
        float4 av[4];
#pragma unroll
        for (int c = 0; c < 4; c++) av[c] = make_float4(0.f, 0.f, 0.f, 0.f);
        if (aok) {
#pragma unroll
            for (int c = 0; c < 4; c++)
                av[c] = *(const float4*)(Arow + k0 + akq + c * 4);
        }
        float4 bv[4];
        bv[0] = *(const float4*)(B + (size_t)(k0 + bkr) * CD + bn + bcol);
        bv[1] = *(const float4*)(B + (size_t)(k0 + bkr) * CD + bn + bcol + 4);
        bv[2] = *(const float4*)(B + (size_t)(k0 + bkr + 16) * CD + bn + bcol);
        bv[3] = *(const float4*)(B + (size_t)(k0 + bkr + 16) * CD + bn + bcol + 4);
        __syncthreads();
#pragma unroll
        for (int c = 0; c < 4; c++) {
            As[akq + c * 4 + 0][arow] = av[c].x;
            As[akq + c * 4 + 1][arow] = av[c].y;
            As[akq + c * 4 + 2][arow] = av[c].z;
            As[akq + c * 4 + 3][arow] = av[c].w;
        }
        *(float4*)&Bs[bkr][bcol]          = bv[0];
        *(float4*)&Bs[bkr][bcol + 4]      = bv[1];
        *(float4*)&Bs[bkr + 16][bcol]     = bv[2];
        *(float4*)&Bs[bkr + 16][bcol + 4] = bv[3];
        __syncthreads();
#pragma unroll
        for (int kk = 0; kk < GBK; kk++) {
            float a0[8], b0[8];
            *(float4*)&a0[0] = *(const float4*)&As[kk][ty * 8];
            *(float4*)&a0[4] = *(const float4*)&As[kk][ty * 8 + 4];
            *(float4*)&b0[0] = *(const float4*)&Bs[kk][tx * 8];
            *(float4*)&b0[4] = *(const float4*)&Bs[kk][tx * 8 + 4];
#pragma unroll
            for (int i = 0; i < 8; i++)
#pragma unroll
                for (int j = 0; j < 8; j++)
                    acc[i][j] = fmaf(a0[i], b0[j], acc[i][j]);
        }
    }
    const int orow = bm + ty * 8, ocol = bn + tx * 8;
#pragma unroll
    for (int i = 0; i < 8; i++) {
        int r = orow + i;
        if (r < n) {
            *(float4*)(C + (size_t)r * CD + ocol) =
                make_float4(acc[i][0], acc[i][1], acc[i][2], acc[i][3]);
            *(float4*)(C + (size_t)r * CD + ocol + 4) =
                make_float4(acc[i][4], acc[i][5], acc[i][6], acc[i][7]);
        }
    }
}

// ===== GEMM over a device-side row list: rows A[rowlist[r]], C scattered back =====
__global__ __launch_bounds__(256) void gemm_f32_gather(
    const float* __restrict__ A, const int* __restrict__ rowlist,
    const int* __restrict__ nrow,
    const float* __restrict__ B0, float* __restrict__ C0)
{
    const int n = *nrow;
    const int bm = blockIdx.x * GBM;
    if (bm >= n) return;
    __shared__ __align__(16) float As[GBK][GBM];
    __shared__ __align__(16) float Bs[GBK][GBN];
    const int bn = blockIdx.y * GBN;
    const int tid = threadIdx.x;
    const int tx = tid & 15, ty = tid >> 4;
    const int arow = tid >> 1, akq = (tid & 1) * 16;
    const int bkr = tid >> 4, bcol = (tid & 15) * 8;
    const int gr = bm + arow;
    const bool aok = (gr < n);
    const float* Arow = A + (size_t)(aok ? rowlist[gr] : 0) * CD;

    float acc[8][8];
#pragma unroll
    for (int i = 0; i < 8; i++)
#pragma unroll
        for (int j = 0; j < 8; j++) acc[i][j] = 0.f;

    for (int k0 = 0; k0 < CD; k0 += GBK) {
        float4 av[4];
#pragma unroll
        for (int c = 0; c < 4; c++) av[c] = make_float4(0.f, 0.f, 0.f, 0.f);
        if (aok) {
#pragma unroll
            for (int c = 0; c < 4; c++)
                av[c] = *(const float4*)(Arow + k0 + akq + c * 4);
        }
        float4 bv[4];
        bv[0] = *(const float4*)(B0 + (size_t)(k0 + bkr) * CD + bn + bcol);
        bv[1] = *(const float4*)(B0 + (size_t)(k0 + bkr) * CD + bn + bcol + 4);
        bv[2] = *(const float4*)(B0 + (size_t)(k0 + bkr + 16) * CD + bn + bcol);
        bv[3] = *(const float4*)(B0 + (size_t)(k0 + bkr + 16) * CD + bn + bcol + 4);
        __syncthreads();
#pragma unroll
        for (int c = 0; c < 4; c++) {
            As[akq + c * 4 + 0][arow] = av[c].x;
            As[akq + c * 4 + 1][arow] = av[c].y;
            As[akq + c * 4 + 2][arow] = av[c].z;
            As[akq + c * 4 + 3][arow] = av[c].w;
        }
        *(float4*)&Bs[bkr][bcol]          = bv[0];
        *(float4*)&Bs[bkr][bcol + 4]      = bv[1];
        *(float4*)&Bs[bkr + 16][bcol]     = bv[2];
        *(float4*)&Bs[bkr + 16][bcol + 4] = bv[3];
        __syncthreads();
#pragma unroll
        for (int kk = 0; kk < GBK; kk++) {
            float a0[8], b0[8];
            *(float4*)&a0[0] = *(const float4*)&As[kk][ty * 8];
            *(float4*)&a0[4] = *(const float4*)&As[kk][ty * 8 + 4];
            *(float4*)&b0[0] = *(const float4*)&Bs[kk][tx * 8];
            *(float4*)&b0[4] = *(const float4*)&Bs[kk][tx * 8 + 4];
#pragma unroll
            for (int i = 0; i < 8; i++)
#pragma unroll
                for (int j = 0; j < 8; j++)
                    acc[i][j] = fmaf(a0[i], b0[j], acc[i][j]);
        }
    }
    const int orow = bm + ty * 8, ocol = bn + tx * 8;
#pragma unroll
    for (int i = 0; i < 8; i++) {
        int r = orow + i;
        if (r < n) {
            int rr = rowlist[r];
            *(float4*)(C0 + (size_t)rr * CD + ocol) =
                make_float4(acc[i][0], acc[i][1], acc[i][2], acc[i][3]);
            *(float4*)(C0 + (size_t)rr * CD + ocol + 4) =
                make_float4(acc[i][4], acc[i][5], acc[i][6], acc[i][7]);
        }
    }
}

// ========== dot_rows: out[r] = H[sel?sel[r]:r] . v   (one wave per row) ==========
__global__ __launch_bounds__(256) void dot_rows(
    const float* __restrict__ H, const int* __restrict__ sel,
    const float* __restrict__ v, float* __restrict__ out, int n)
{
    const int lane = threadIdx.x & 63;
    const int r = blockIdx.x * 4 + (threadIdx.x >> 6);
    if (r >= n) return;
    const int row = sel ? sel[r] : r;
    const float* h = H + (size_t)row * CD;
    float4 a0 = *(const float4*)(h + lane * 8);
    float4 a1 = *(const float4*)(h + lane * 8 + 4);
    float4 b0 = *(const float4*)(v + lane * 8);
    float4 b1 = *(const float4*)(v + lane * 8 + 4);
    float sv = a0.x * b0.x + a0.y * b0.y + a0.z * b0.z + a0.w * b0.w
             + a1.x * b1.x + a1.y * b1.y + a1.z * b1.z + a1.w * b1.w;
#pragma unroll
    for (int o = 32; o; o >>= 1) sv += __shfl_xor(sv, o, 64);
    if (lane == 0) out[r] = sv;
}

// === dot over device row list, scatter result to out[rowlist[r]] ===
__global__ __launch_bounds__(256) void dot_rows_gather(
    const float* __restrict__ H, const int* __restrict__ rowlist,
    const int* __restrict__ nrow,
    const float* __restrict__ v, float* __restrict__ out)
{
    const int lane = threadIdx.x & 63;
    const int r = blockIdx.x * 4 + (threadIdx.x >> 6);
    if (r >= *nrow) return;
    const int row = rowlist[r];
    const float* h = H + (size_t)row * CD;
    float4 a0 = *(const float4*)(h + lane * 8);
    float4 a1 = *(const float4*)(h + lane * 8 + 4);
    float4 b0 = *(const float4*)(v + lane * 8);
    float4 b1 = *(const float4*)(v + lane * 8 + 4);
    float sv = a0.x * b0.x + a0.y * b0.y + a0.z * b0.z + a0.w * b0.w
             + a1.x * b1.x + a1.y * b1.y + a1.z * b1.z + a1.w * b1.w;
#pragma unroll
    for (int o = 32; o; o >>= 1) sv += __shfl_xor(sv, o, 64);
    if (lane == 0) out[row] = sv;
}

// ========== wa_gemv6: wa[l][k] = sum_j W[l][k][j] * a[l][CD + j], l = 0..5 ==========
__global__ __launch_bounds__(256) void wa_gemv6(
    const float* __restrict__ W6, const float* __restrict__ a6, float* __restrict__ wa)
{
    const int layer = blockIdx.y;
    const int lane = threadIdx.x & 63;
    const int r = blockIdx.x * 4 + (threadIdx.x >> 6);
    const float* Wr = W6 + (size_t)layer * CDCD + (size_t)r * CD;
    const float* ah = a6 + layer * 2 * CD + CD;
    float4 a0 = *(const float4*)(Wr + lane * 8);
    float4 a1 = *(const float4*)(Wr + lane * 8 + 4);
    float4 b0 = *(const float4*)(ah + lane * 8);
    float4 b1 = *(const float4*)(ah + lane * 8 + 4);
    float sv = a0.x * b0.x + a0.y * b0.y + a0.z * b0.z + a0.w * b0.w
             + a1.x * b1.x + a1.y * b1.y + a1.z * b1.z + a1.w * b1.w;
#pragma unroll
    for (int o = 32; o; o >>= 1) sv += __shfl_xor(sv, o, 64);
    if (lane == 0) wa[layer * CD + r] = sv;
}

// ================= parallel CSR build =================
struct Csr6 {
    const int* src[6]; const int* dst[6];
    int* cnt[6]; int* off[6]; int* cur[6]; int* srcs[6];
    int nd[6]; int base[6]; int ecum[7];
};

__global__ __launch_bounds__(256) void zero_ints(int* __restrict__ p, int n)
{
    for (int i = blockIdx.x * 256 + threadIdx.x; i < n; i += gridDim.x * 256)
        p[i] = 0;
}

__global__ __launch_bounds__(256) void csr_hist(Csr6 G)
{
    const int total = G.ecum[6];
    for (int idx = blockIdx.x * 256 + threadIdx.x; idx < total; idx += gridDim.x * 256) {
        int g = 0;
        while (idx >= G.ecum[g + 1]) g++;
        int e = idx - G.ecum[g];
        atomicAdd(&G.cnt[g][G.dst[g][e] - G.base[g]], 1);
    }
}

__global__ __launch_bounds__(1024) void csr_scan(Csr6 G)
{
    __shared__ int wsum[16];
    const int g = blockIdx.x;
    const int tid = threadIdx.x, lane = tid & 63, wid = tid >> 6;
    const int n = G.nd[g];
    int* cnt = G.cnt[g];
    int* off = G.off[g];
    int* cur = G.cur[g];

    int running = 0;
    for (int base = 0; base < n; base += 1024) {
        int idx = base + tid;
        int v0 = (idx < n) ? cnt[idx] : 0;
        int v = v0;
#pragma unroll
        for (int dlt = 1; dlt < 64; dlt <<= 1) {
            int t = __shfl_up(v, dlt, 64);
            if (lane >= dlt) v += t;
        }
        if (lane == 63) wsum[wid] = v;
        __syncthreads();
        if (wid == 0) {
            int wv = (lane < 16) ? wsum[lane] : 0;
#pragma unroll
            for (int dlt = 1; dlt < 16; dlt <<= 1) {
                int t = __shfl_up(wv, dlt, 64);
                if (lane >= dlt) wv += t;
            }
            if (lane < 16) wsum[lane] = wv;
        }
        __syncthreads();
        int wprefix = (wid > 0) ? wsum[wid - 1] : 0;
        int chunk_total = wsum[15];
        int excl = running + wprefix + (v - v0);
        if (idx < n) { off[idx] = excl; cur[idx] = excl; }
        running += chunk_total;
        __syncthreads();
    }
    if (tid == 0) off[n] = running;
}

__global__ __launch_bounds__(256) void csr_scatter(Csr6 G)
{
    const int total = G.ecum[6];
    for (int idx = blockIdx.x * 256 + threadIdx.x; idx < total; idx += gridDim.x * 256) {
        int g = 0;
        while (idx >= G.ecum[g + 1]) g++;
        int e = idx - G.ecum[g];
        int dl = G.dst[g][e] - G.base[g];
        int pos = atomicAdd(&G.cur[g][dl], 1);
        G.srcs[g][pos] = G.src[g][e];
    }
}

// ===== mark the user rows that feed fusion-2's l5 (sources of eu edges with dst in qsel) =====
__global__ void mark_qsel(const int* __restrict__ qid, int* __restrict__ qsel)
{
    qsel[qid[threadIdx.x]] = 1;   // 1 block x 128
}

__global__ __launch_bounds__(256) void mark_l5(
    const int* __restrict__ esrc, const int* __restrict__ edst, int ne,
    const int* __restrict__ qsel, int* __restrict__ umark,
    int* __restrict__ list, int* __restrict__ nlist)
{
    for (int e = blockIdx.x * 256 + threadIdx.x; e < ne; e += gridDim.x * 256) {
        if (qsel[edst[e]]) {
            int u = esrc[e] - QN;
            if (atomicExch(&umark[u], 1) == 0)
                list[atomicAdd(nlist, 1)] = u;
        }
    }
}

// ================= GAT aggregate: one block per (possibly selected) dst node ======
__global__ __launch_bounds__(256) void gat_aggregate(
    const int* __restrict__ off, const int* __restrict__ srcs, int src_base,
    const int* __restrict__ sel,
    const float* __restrict__ z, const float* __restrict__ s,
    const float* __restrict__ dvals,
    const float* __restrict__ base, float* __restrict__ out)
{
    const int b = blockIdx.x;
    const int node = sel ? sel[b] : b;
    const int tid = threadIdx.x;
    const int lane = tid & 63, wid = tid >> 6;
    const int beg = off[node], end = off[node + 1];

    float2 bacc = base ? *(const float2*)(base + (size_t)node * CD + tid * 2)
                       : make_float2(0.f, 0.f);
    if (beg == end) {
        *(float2*)(out + (size_t)b * CD + tid * 2) = bacc;
        return;
    }
    const float dd = dvals[b];

    float m = -1e30f, den = 0.f;
    for (int e = beg + tid; e < end; e += 256) {
        float sc = s[srcs[e] - src_base] + dd;
        sc = sc > 0.f ? sc : 0.01f * sc;
        if (sc > m) { den = den * __expf(m - sc) + 1.f; m = sc; }
        else den += __expf(sc - m);
    }
#pragma unroll
    for (int o = 32; o; o >>= 1) {
        float om = __shfl_xor(m, o, 64);
        float od = __shfl_xor(den, o, 64);
        float nm = fmaxf(m, om);
        den = den * __expf(m - nm) + od * __expf(om - nm);
        m = nm;
    }
    __shared__ float wm[4], wd[4];
    __shared__ float alpha_s[256];
    __shared__ int   src_s[256];
    if (lane == 0) { wm[wid] = m; wd[wid] = den; }
    __syncthreads();
    float M = fmaxf(fmaxf(wm[0], wm[1]), fmaxf(wm[2], wm[3]));
    float Dn = wd[0] * __expf(wm[0] - M) + wd[1] * __expf(wm[1] - M)
             + wd[2] * __expf(wm[2] - M) + wd[3] * __expf(wm[3] - M);
    float invD = 1.f / Dn;

    for (int c0 = beg; c0 < end; c0 += 256) {
        int e = c0 + tid;
        float al = 0.f; int sr = 0;
        if (e < end) {
            sr = srcs[e] - src_base;
            float sc = s[sr] + dd;
            sc = sc > 0.f ? sc : 0.01f * sc;
            al = __expf(sc - M) * invD;
        }
        __syncthreads();
        alpha_s[tid] = al; src_s[tid] = sr;
        __syncthreads();
        int cc = min(256, end - c0);
        for (int jj = 0; jj < cc; jj++) {
            const float* zr = z + (size_t)src_s[jj] * CD;
            float a = alpha_s[jj];
            float2 v = *(const float2*)(zr + tid * 2);
            bacc.x = fmaf(a, v.x, bacc.x);
            bacc.y = fmaf(a, v.y, bacc.y);
        }
    }
    *(float2*)(out + (size_t)b * CD + tid * 2) = bacc;
}

// ================= attention fuse for kn =================
__global__ __launch_bounds__(256) void fuse_kn(
    const float* __restrict__ kn, const float* __restrict__ kd,
    const float* __restrict__ ku, const float* __restrict__ Dm,
    const float* __restrict__ aw, const float* __restrict__ ab, float* __restrict__ out)
{
    const int i = blockIdx.x, tid = threadIdx.x;
    const int lane = tid & 63, wid = tid >> 6;
    const size_t ro = (size_t)i * CD + tid * 2;
    const int c = tid * 2;
    float2 vkn = *(const float2*)(kn + ro);
    float2 v1  = *(const float2*)(kd + ro);
    float2 v2  = *(const float2*)(ku + ro);
    float2 v3  = *(const float2*)(Dm + ro);
    float p1 = vkn.x*aw[c]      + vkn.y*aw[c+1]      + v1.x*aw[CD+c]      + v1.y*aw[CD+c+1];
    float p2 = vkn.x*aw[1024+c] + vkn.y*aw[1024+c+1] + v2.x*aw[1024+CD+c] + v2.y*aw[1024+CD+c+1];
    float p3 = vkn.x*aw[2048+c] + vkn.y*aw[2048+c+1] + v3.x*aw[2048+CD+c] + v3.y*aw[2048+CD+c+1];
#pragma unroll
    for (int o = 32; o; o >>= 1) {
        p1 += __shfl_xor(p1, o, 64); p2 += __shfl_xor(p2, o, 64); p3 += __shfl_xor(p3, o, 64);
    }
    __shared__ float r1[4], r2[4], r3[4];
    if (lane == 0) { r1[wid] = p1; r2[wid] = p2; r3[wid] = p3; }
    __syncthreads();
    float s1 = r1[0]+r1[1]+r1[2]+r1[3] + ab[0];
    float s2 = r2[0]+r2[1]+r2[2]+r2[3] + ab[1];
    float s3 = r3[0]+r3[1]+r3[2]+r3[3] + ab[2];
    float mm = fmaxf(s1, fmaxf(s2, s3));
    float e1 = __expf(s1-mm), e2 = __expf(s2-mm), e3 = __expf(s3-mm);
    float inv = 1.f / (e1 + e2 + e3);
    float w1 = e1*inv, w2 = e2*inv, w3 = e3*inv;
    float2 o_;
    o_.x = vkn.x + w1*v1.x + w2*v2.x + w3*v3.x;
    o_.y = vkn.y + w1*v1.y + w2*v2.y + w3*v3.y;
    *(float2*)(out + ro) = o_;
}

// ================= attention fuse for ex (optionally row-selected) =================
__global__ __launch_bounds__(256) void fuse_ex(
    const float* __restrict__ ex, const int* __restrict__ sel,
    const float* __restrict__ Bq, const float* __restrict__ Cq,
    const float* __restrict__ aw, const float* __restrict__ ab, float* __restrict__ out)
{
    const int i = blockIdx.x, tid = threadIdx.x;
    const int lane = tid & 63, wid = tid >> 6;
    const int exrow = sel ? sel[i] : i;
    const size_t eo = (size_t)exrow * CD + tid * 2;
    const size_t ro = (size_t)i * CD + tid * 2;
    const int c = tid * 2;
    float2 ve = *(const float2*)(ex + eo);
    float2 vb = *(const float2*)(Bq + ro);
    float2 vc = *(const float2*)(Cq + ro);
    const float* a3 = aw + 3 * 2 * CD;
    const float* a4 = aw + 4 * 2 * CD;
    float p1 = ve.x*a3[c] + ve.y*a3[c+1] + vb.x*a3[CD+c] + vb.y*a3[CD+c+1];
    float p2 = ve.x*a4[c] + ve.y*a4[c+1] + vc.x*a4[CD+c] + vc.y*a4[CD+c+1];
#pragma unroll
    for (int o = 32; o; o >>= 1) { p1 += __shfl_xor(p1, o, 64); p2 += __shfl_xor(p2, o, 64); }
    __shared__ float r1[4], r2[4];
    if (lane == 0) { r1[wid] = p1; r2[wid] = p2; }
    __syncthreads();
    float t1 = r1[0]+r1[1]+r1[2]+r1[3] + ab[3];
    float t2 = r2[0]+r2[1]+r2[2]+r2[3] + ab[4];
    float mm = fmaxf(t1, t2);
    float e1 = __expf(t1-mm), e2 = __expf(t2-mm);
    float inv = 1.f / (e1 + e2);
    float w1 = e1*inv, w2 = e2*inv;
    float2 o_;
    o_.x = ve.x + w1*vb.x + w2*vc.x;
    o_.y = ve.y + w1*vb.y + w2*vc.y;
    *(float2*)(out + ro) = o_;
}

// ===== final prediction, q_table-sparse: only ~5 of 512 concepts have qb!=0 =====
__global__ __launch_bounds__(256) void final_pred(
    const float* __restrict__ sP, const float* __restrict__ kP,
    const float* __restrict__ dP, const float* __restrict__ kD,
    const float* __restrict__ W3, const float* __restrict__ b3,
    const float* __restrict__ q_table, const int* __restrict__ qid,
    float* __restrict__ out)
{
    const int b = blockIdx.x;
    const int tid = threadIdx.x, lane = tid & 63, wid = tid >> 6;
    __shared__ int   sidx[CD];
    __shared__ float sqv[CD];
    __shared__ int   snn;
    __shared__ float scnt[4], sacc[4];
    if (tid == 0) snn = 0;
    __syncthreads();
    const float* qrow = q_table + (size_t)qid[b] * CD;
    float cnt = 0.f;
    for (int i = tid; i < CD; i += 256) {
        float qv = qrow[i];
        if (qv != 0.f) {
            int p = atomicAdd(&snn, 1);
            sidx[p] = i; sqv[p] = qv;
            cnt += qv;
        }
    }
#pragma unroll
    for (int o = 32; o; o >>= 1) cnt += __shfl_xor(cnt, o, 64);
    if (lane == 0) scnt[wid] = cnt;
    __syncthreads();
    const int nn = snn;
    const float bb = b3[0];
    const float* sPr = sP + (size_t)b * CD;
    const float* dPr = dP + (size_t)b * CD;
    float acc = 0.f;
    for (int t = wid; t < nn; t += 4) {
        const int i = sidx[t];
        const float* kPr = kP + (size_t)i * CD;
        const float* kDr = kD + (size_t)i * CD;
        float o = 0.f;
#pragma unroll
        for (int p = 0; p < 8; p++) {
            int j = lane + (p << 6);
            float pv = sPr[j] + kPr[j];
            float dv = dPr[j] + kDr[j];
            float s1 = 1.f / (1.f + __expf(-pv));
            float s2 = 1.f / (1.f + __expf(-dv));
            o += (s1 - s2) * W3[j];
        }
#pragma unroll
        for (int ofs = 32; ofs; ofs >>= 1) o += __shfl_xor(o, ofs, 64);
        if (lane == 0) acc += sqv[t] / (1.f + __expf(-(o + bb)));
    }
    if (lane == 0) sacc[wid] = acc;
    __syncthreads();
    if (tid == 0)
        out[b] = (sacc[0] + sacc[1] + sacc[2] + sacc[3])
               / (scnt[0] + scnt[1] + scnt[2] + scnt[3]);
}

// ================= host orchestration =================
extern "C" void kernel_launch(void* const* d_in, const int* in_sizes, int n_in,
                              void* d_out, int out_size, void* d_ws, size_t ws_size,
                              hipStream_t stream)
{
    const int*   user_id      = (const int*)d_in[0];
    const int*   question_id  = (const int*)d_in[1];
    const float* q_table      = (const float*)d_in[2];
    const int*   e_dir        = (const int*)d_in[3];
    const int*   e_und        = (const int*)d_in[4];
    const int*   e_ke         = (const int*)d_in[5];
    const int*   e_ek         = (const int*)d_in[6];
    const int*   e_ue         = (const int*)d_in[7];
    const int*   e_eu         = (const int*)d_in[8];
    const float* user_emb     = (const float*)d_in[9];
    const float* question_emb = (const float*)d_in[10];
    const float* concept_emb  = (const float*)d_in[11];
    const float* gat_W        = (const float*)d_in[12];
    const float* gat_a        = (const float*)d_in[13];
    const float* attn_w       = (const float*)d_in[14];
    const float* attn_b       = (const float*)d_in[15];
    const float* W1           = (const float*)d_in[16];
    const float* W2           = (const float*)d_in[17];
    const float* W3           = (const float*)d_in[18];
    const float* b3           = (const float*)d_in[19];
    float* out = (float*)d_out;

    char* wptr = (char*)d_ws;
    auto alloc = [&](size_t bytes) -> void* {
        void* p = (void*)wptr;
        wptr += (bytes + 255) & ~(size_t)255;
        return p;
    };

    // z zone: z2/z4 live in [0, 8000) and [8000, 16000); z5 reuses [0, 20000)
    float* zone = (float*)alloc((size_t)UN * CD * 4);
    float* z2 = zone;
    float* z4 = zone + (size_t)QN * CD;
    float* z5 = zone;
    float* z0 = (float*)alloc((size_t)CD * CD * 4);
    float* z1 = (float*)alloc((size_t)CD * CD * 4);
    float* z3 = (float*)alloc((size_t)CD * CD * 4);

    float* s0 = (float*)alloc((size_t)CD * 4);
    float* s1 = (float*)alloc((size_t)CD * 4);
    float* s2 = (float*)alloc((size_t)QN * 4);
    float* s3 = (float*)alloc((size_t)CD * 4);
    float* s4 = (float*)alloc((size_t)QN * 4);
    float* s5 = (float*)alloc((size_t)UN * 4);
    float* dv0 = (float*)alloc((size_t)CD * 4);
    float* dv1 = (float*)alloc((size_t)CD * 4);
    float* dv2 = (float*)alloc((size_t)CD * 4);
    float* dv3 = (float*)alloc((size_t)QN * 4);
    float* dv4 = (float*)alloc((size_t)UN * 4);
    float* dv5 = (float*)alloc((size_t)QN * 4);
    float* wa  = (float*)alloc((size_t)6 * CD * 4);

    float* kn1  = (float*)alloc((size_t)CD * CD * 4);
    float* ex1  = (float*)alloc((size_t)QN * CD * 4);
    float* stu1 = (float*)alloc((size_t)UN * CD * 4);
    float* kn2  = (float*)alloc((size_t)CD * CD * 4);
    float* kdir = (float*)alloc((size_t)CD * CD * 4);
    float* kund = (float*)alloc((size_t)CD * CD * 4);
    float* Dm   = (float*)alloc((size_t)CD * CD * 4);
    float* Bq   = (float*)alloc((size_t)QN * CD * 4);
    float* Cq   = (float*)alloc((size_t)QN * CD * 4);
    float* eb   = (float*)alloc((size_t)BATCHN * CD * 4);
    float* sb   = (float*)alloc((size_t)BATCHN * CD * 4);
    float* sP   = (float*)alloc((size_t)BATCHN * CD * 4);
    float* dP   = (float*)alloc((size_t)BATCHN * CD * 4);
    float* kP   = (float*)alloc((size_t)CD * CD * 4);
    float* kD   = (float*)alloc((size_t)CD * CD * 4);

    static const int g_ne[6]   = {4096, 8192, 40000, 40000, 100000, 100000};
    static const int g_nd[6]   = {512, 512, 512, QN, UN, QN};
    static const int g_base[6] = {0, 0, QN, 0, QN, 0};
    const int* g_edges[6] = {e_dir, e_und, e_ke, e_ek, e_ue, e_eu};

    // zeroed region: cnt6 | qsel | umark | nlist  (contiguous)
    int cnt_total = 0;
    for (int g = 0; g < 6; g++) cnt_total += g_nd[g];
    int* zbase = (int*)alloc((size_t)(cnt_total + QN + UN + 1) * 4);
    int* cnt6[6];
    {
        int o = 0;
        for (int g = 0; g < 6; g++) { cnt6[g] = zbase + o; o += g_nd[g]; }
    }
    int* qsel  = zbase + cnt_total;
    int* umark = qsel + QN;
    int* nlist = umark + UN;
    const int ZTOT = cnt_total + QN + UN + 1;

    int* cur6 = (int*)alloc((size_t)cnt_total * 4);
    int* list = (int*)alloc((size_t)UN * 4);
    int* off[6]; int* srcs[6];
    for (int g = 0; g < 6; g++) {
        off[g]  = (int*)alloc((size_t)(g_nd[g] + 1) * 4);
        srcs[g] = (int*)alloc((size_t)g_ne[g] * 4);
    }

    Csr6 G;
    {
        int o = 0, ec = 0;
        for (int g = 0; g < 6; g++) {
            G.src[g] = g_edges[g];
            G.dst[g] = g_edges[g] + g_ne[g];
            G.cnt[g] = cnt6[g];
            G.off[g] = off[g];
            G.cur[g] = cur6 + o;
            G.srcs[g] = srcs[g];
            G.nd[g] = g_nd[g];
            G.base[g] = g_base[g];
            G.ecum[g] = ec;
            o += g_nd[g]; ec += g_ne[g];
        }
        G.ecum[6] = ec;
    }

    zero_ints<<<128, 256, 0, stream>>>(zbase, ZTOT);
    csr_hist<<<512, 256, 0, stream>>>(G);
    csr_scan<<<6, 1024, 0, stream>>>(G);
    csr_scatter<<<512, 256, 0, stream>>>(G);
    mark_qsel<<<1, BATCHN, 0, stream>>>(question_id, qsel);
    mark_l5<<<200, 256, 0, stream>>>(e_eu, e_eu + 100000, 100000, qsel, umark, list, nlist);

    auto gemm = [&](const float* A, int n, const float* B0, float* C0,
                    const float* B1, float* C1) {
        dim3 g((n + GBM - 1) / GBM, B1 ? 8 : 4);
        gemm_f32<<<g, 256, 0, stream>>>(A, n, B0, C0, B1, C1);
    };
    auto dots = [&](const float* H, const int* sel, const float* v, float* o, int n) {
        dot_rows<<<(n + 3) / 4, 256, 0, stream>>>(H, sel, v, o, n);
    };
    auto agg = [&](int g, int src_base, const int* sel, const float* z, const float* s,
                   const float* dv, const float* base, float* o, int nblk) {
        gat_aggregate<<<nblk, 256, 0, stream>>>(off[g], srcs[g], src_base, sel,
                                                z, s, dv, base, o);
    };

    auto run_fusion = [&](int f, const float* kn, const float* ex, const float* stu,
                          const int* selq, const int* selu, int nd3, int nd4, int nd5,
                          float* kn_o, float* ex_o, float* stu_o) {
        const float* Wf  = gat_W  + (size_t)f * 6 * CDCD;
        const float* af  = gat_a  + (size_t)f * 6 * 2 * CD;
        const float* awf = attn_w + (size_t)f * 5 * 2 * CD;
        const float* abf = attn_b + (size_t)f * 5;

        wa_gemv6<<<dim3(128, 6), 256, 0, stream>>>(Wf, af, wa);

        // l0 + l1 (A = kn, dual B)
        gemm(kn, CD, Wf + 0 * CDCD, z0, Wf + 1 * CDCD, z1);
        dots(z0, nullptr, af + 0 * 2 * CD, s0, CD);
        dots(z1, nullptr, af + 1 * 2 * CD, s1, CD);
        dots(kn, nullptr, wa + 0 * CD, dv0, CD);
        dots(kn, nullptr, wa + 1 * CD, dv1, CD);
        agg(0, 0, nullptr, z0, s0, dv0, nullptr, kdir, CD);
        agg(1, 0, nullptr, z1, s1, dv1, nullptr, kund, CD);

        // l2 + l4 (A = ex, dual B)
        gemm(ex, QN, Wf + 2 * CDCD, z2, Wf + 4 * CDCD, z4);
        dots(z2, nullptr, af + 2 * 2 * CD, s2, QN);
        dots(kn, nullptr, wa + 2 * CD, dv2, CD);
        agg(2, 0, nullptr, z2, s2, dv2, nullptr, Dm, CD);

        // l3 (A = kn; sources of ek are the concept rows of ekg)
        gemm(kn, CD, Wf + 3 * CDCD, z3, nullptr, nullptr);
        dots(z3, nullptr, af + 3 * 2 * CD, s3, CD);
        dots(ex, selq, wa + 3 * CD, dv3, nd3);
        agg(3, QN, selq, z3, s3, dv3, nullptr, Bq, nd3);

        // l4 (z4 already computed; sources of ue are the ex rows of eug)
        dots(z4, nullptr, af + 4 * 2 * CD, s4, QN);
        dots(stu, selu, wa + 4 * CD, dv4, nd4);
        agg(4, 0, selu, z4, s4, dv4, stu, stu_o, nd4);

        // l5 (A = stu; z5 overwrites zone AFTER l2/l4 aggregates consumed it)
        if (!selq) {
            gemm(stu, UN, Wf + 5 * CDCD, z5, nullptr, nullptr);
            dots(z5, nullptr, af + 5 * 2 * CD, s5, UN);
        } else {
            // fusion 2: only ~1600 of 20000 user rows feed the 128 selected questions
            dim3 gg((UN + GBM - 1) / GBM, 4);
            gemm_f32_gather<<<gg, 256, 0, stream>>>(stu, list, nlist, Wf + 5 * CDCD, z5);
            dot_rows_gather<<<(UN + 3) / 4, 256, 0, stream>>>(z5, list, nlist,
                                                              af + 5 * 2 * CD, s5);
        }
        dots(ex, selq, wa + 5 * CD, dv5, nd5);
        agg(5, QN, selq, z5, s5, dv5, nullptr, Cq, nd5);

        fuse_kn<<<CD, 256, 0, stream>>>(kn, kdir, kund, Dm, awf, abf, kn_o);
        fuse_ex<<<nd3, 256, 0, stream>>>(ex, selq, Bq, Cq, awf, abf, ex_o);
    };

    run_fusion(0, concept_emb, question_emb, user_emb,
               nullptr, nullptr, QN, UN, QN, kn1, ex1, stu1);
    run_fusion(1, kn1, ex1, stu1,
               question_id, user_id, BATCHN, BATCHN, BATCHN, kn2, eb, sb);

    // prediction head
    gemm(sb, BATCHN, W1, sP, nullptr, nullptr);
    gemm(eb, BATCHN, W2, dP, nullptr, nullptr);
    gemm(kn2, CD, W1 + (size_t)CDCD, kP, W2 + (size_t)CDCD, kD);
    final_pred<<<BATCHN, 256, 0, stream>>>(sP, kP, dP, kD, W3, b3, q_table, question_id, out);
}

// Round 5
// 1264.631 us; speedup vs baseline: 1.5360x; 1.1534x over previous
//
#include <hip/hip_runtime.h>
#include <math.h>

#define CD 512
#define CDCD (CD * CD)
#define QN 8000
#define UN 20000
#define BATCHN 128

typedef unsigned short u16;
typedef unsigned int u32;
typedef __attribute__((ext_vector_type(8))) __bf16 bf16x8;
typedef __attribute__((ext_vector_type(4))) float f32x4;

static __device__ __forceinline__ u16 f2bf(float x) {
    u32 u = __float_as_uint(x);
    return (u16)((u + 0x7fff + ((u >> 16) & 1)) >> 16);
}
static __device__ __forceinline__ float bf2f(u16 h) {
    return __uint_as_float(((u32)h) << 16);
}
static __device__ __forceinline__ u32 pck(u16 a, u16 b) {
    return (u32)a | ((u32)b << 16);
}

// ================= fp32 SIMT GEMM (small/medium cases) =================
#define GBM 128
#define GBN 128
#define GBK 32

__global__ __launch_bounds__(256) void gemm_f32(
    const float* __restrict__ A, int n,
    const float* __restrict__ B0, float* __restrict__ C0,
    const float* __restrict__ B1, float* __restrict__ C1)
{
    __shared__ __align__(16) float As[GBK][GBM];
    __shared__ __align__(16) float Bs[GBK][GBN];
    const int which = blockIdx.y >> 2;
    const float* __restrict__ B = which ? B1 : B0;
    float* __restrict__ C = which ? C1 : C0;
    const int bm = blockIdx.x * GBM, bn = (blockIdx.y & 3) * GBN;
    const int tid = threadIdx.x;
    const int tx = tid & 15, ty = tid >> 4;
    const int arow = tid >> 1, akq = (tid & 1) * 16;
    const int bkr = tid >> 4, bcol = (tid & 15) * 8;
    const int gr = bm + arow;
    const bool aok = (gr < n);
    const float* Arow = A + (size_t)(aok ? gr : 0) * CD;

    float acc[8][8];
#pragma unroll
    for (int i = 0; i < 8; i++)
#pragma unroll
        for (int j = 0; j < 8; j++) acc[i][j] = 0.f;

    for (int k0 = 0; k0 < CD; k0 += GBK) {
        float4 av[4];
#pragma unroll
        for (int c = 0; c < 4; c++) av[c] = make_float4(0.f, 0.f, 0.f, 0.f);
        if (aok) {
#pragma unroll
            for (int c = 0; c < 4; c++)
                av[c] = *(const float4*)(Arow + k0 + akq + c * 4);
        }
        float4 bv[4];
        bv[0] = *(const float4*)(B + (size_t)(k0 + bkr) * CD + bn + bcol);
        bv[1] = *(const float4*)(B + (size_t)(k0 + bkr) * CD + bn + bcol + 4);
        bv[2] = *(const float4*)(B + (size_t)(k0 + bkr + 16) * CD + bn + bcol);
        bv[3] = *(const float4*)(B + (size_t)(k0 + bkr + 16) * CD + bn + bcol + 4);
        __syncthreads();
#pragma unroll
        for (int c = 0; c < 4; c++) {
            As[akq + c * 4 + 0][arow] = av[c].x;
            As[akq + c * 4 + 1][arow] = av[c].y;
            As[akq + c * 4 + 2][arow] = av[c].z;
            As[akq + c * 4 + 3][arow] = av[c].w;
        }
        *(float4*)&Bs[bkr][bcol]          = bv[0];
        *(float4*)&Bs[bkr][bcol + 4]      = bv[1];
        *(float4*)&Bs[bkr + 16][bcol]     = bv[2];
        *(float4*)&Bs[bkr + 16][bcol + 4] = bv[3];
        __syncthreads();
#pragma unroll
        for (int kk = 0; kk < GBK; kk++) {
            float a0[8], b0[8];
            *(float4*)&a0[0] = *(const float4*)&As[kk][ty * 8];
            *(float4*)&a0[4] = *(const float4*)&As[kk][ty * 8 + 4];
            *(float4*)&b0[0] = *(const float4*)&Bs[kk][tx * 8];
            *(float4*)&b0[4] = *(const float4*)&Bs[kk][tx * 8 + 4];
#pragma unroll
            for (int i = 0; i < 8; i++)
#pragma unroll
                for (int j = 0; j < 8; j++)
                    acc[i][j] = fmaf(a0[i], b0[j], acc[i][j]);
        }
    }
    const int orow = bm + ty * 8, ocol = bn + tx * 8;
#pragma unroll
    for (int i = 0; i < 8; i++) {
        int r = orow + i;
        if (r < n) {
            *(float4*)(C + (size_t)r * CD + ocol) =
                make_float4(acc[i][0], acc[i][1], acc[i][2], acc[i][3]);
            *(float4*)(C + (size_t)r * CD + ocol + 4) =
                make_float4(acc[i][4], acc[i][5], acc[i][6], acc[i][7]);
        }
    }
}

// ===== fp32 GEMM over a device-side row list (f2 l5 sparse path) =====
__global__ __launch_bounds__(256) void gemm_f32_gather(
    const float* __restrict__ A, const int* __restrict__ rowlist,
    const int* __restrict__ nrow,
    const float* __restrict__ B0, float* __restrict__ C0)
{
    const int n = *nrow;
    const int bm = blockIdx.x * GBM;
    if (bm >= n) return;
    __shared__ __align__(16) float As[GBK][GBM];
    __shared__ __align__(16) float Bs[GBK][GBN];
    const int bn = blockIdx.y * GBN;
    const int tid = threadIdx.x;
    const int tx = tid & 15, ty = tid >> 4;
    const int arow = tid >> 1, akq = (tid & 1) * 16;
    const int bkr = tid >> 4, bcol = (tid & 15) * 8;
    const int gr = bm + arow;
    const bool aok = (gr < n);
    const float* Arow = A + (size_t)(aok ? rowlist[gr] : 0) * CD;

    float acc[8][8];
#pragma unroll
    for (int i = 0; i < 8; i++)
#pragma unroll
        for (int j = 0; j < 8; j++) acc[i][j] = 0.f;

    for (int k0 = 0; k0 < CD; k0 += GBK) {
        float4 av[4];
#pragma unroll
        for (int c = 0; c < 4; c++) av[c] = make_float4(0.f, 0.f, 0.f, 0.f);
        if (aok) {
#pragma unroll
            for (int c = 0; c < 4; c++)
                av[c] = *(const float4*)(Arow + k0 + akq + c * 4);
        }
        float4 bv[4];
        bv[0] = *(const float4*)(B0 + (size_t)(k0 + bkr) * CD + bn + bcol);
        bv[1] = *(const float4*)(B0 + (size_t)(k0 + bkr) * CD + bn + bcol + 4);
        bv[2] = *(const float4*)(B0 + (size_t)(k0 + bkr + 16) * CD + bn + bcol);
        bv[3] = *(const float4*)(B0 + (size_t)(k0 + bkr + 16) * CD + bn + bcol + 4);
        __syncthreads();
#pragma unroll
        for (int c = 0; c < 4; c++) {
            As[akq + c * 4 + 0][arow] = av[c].x;
            As[akq + c * 4 + 1][arow] = av[c].y;
            As[akq + c * 4 + 2][arow] = av[c].z;
            As[akq + c * 4 + 3][arow] = av[c].w;
        }
        *(float4*)&Bs[bkr][bcol]          = bv[0];
        *(float4*)&Bs[bkr][bcol + 4]      = bv[1];
        *(float4*)&Bs[bkr + 16][bcol]     = bv[2];
        *(float4*)&Bs[bkr + 16][bcol + 4] = bv[3];
        __syncthreads();
#pragma unroll
        for (int kk = 0; kk < GBK; kk++) {
            float a0[8], b0[8];
            *(float4*)&a0[0] = *(const float4*)&As[kk][ty * 8];
            *(float4*)&a0[4] = *(const float4*)&As[kk][ty * 8 + 4];
            *(float4*)&b0[0] = *(const float4*)&Bs[kk][tx * 8];
            *(float4*)&b0[4] = *(const float4*)&Bs[kk][tx * 8 + 4];
#pragma unroll
            for (int i = 0; i < 8; i++)
#pragma unroll
                for (int j = 0; j < 8; j++)
                    acc[i][j] = fmaf(a0[i], b0[j], acc[i][j]);
        }
    }
    const int orow = bm + ty * 8, ocol = bn + tx * 8;
#pragma unroll
    for (int i = 0; i < 8; i++) {
        int r = orow + i;
        if (r < n) {
            int rr = rowlist[r];
            *(float4*)(C0 + (size_t)rr * CD + ocol) =
                make_float4(acc[i][0], acc[i][1], acc[i][2], acc[i][3]);
            *(float4*)(C0 + (size_t)rr * CD + ocol + 4) =
                make_float4(acc[i][4], acc[i][5], acc[i][6], acc[i][7]);
        }
    }
}

// ========= conv_a: fp32 activations -> split bf16 hi/lo, layout [64][n_pad][8] =========
// grid (n_pad/256, 64); rows >= n write zeros.
__global__ __launch_bounds__(256) void conv_a(
    const float* __restrict__ src, u16* __restrict__ h, u16* __restrict__ l, int n)
{
    const int row = blockIdx.x * 256 + threadIdx.x;
    const int kc = blockIdx.y;
    const int n_pad = gridDim.x * 256;
    float4 v0 = make_float4(0.f, 0.f, 0.f, 0.f), v1 = v0;
    if (row < n) {
        v0 = *(const float4*)(src + (size_t)row * CD + kc * 8);
        v1 = *(const float4*)(src + (size_t)row * CD + kc * 8 + 4);
    }
    float a[8] = {v0.x, v0.y, v0.z, v0.w, v1.x, v1.y, v1.z, v1.w};
    u16 hh[8], ll[8];
#pragma unroll
    for (int e = 0; e < 8; e++) {
        hh[e] = f2bf(a[e]);
        ll[e] = f2bf(a[e] - bf2f(hh[e]));
    }
    size_t o = ((size_t)kc * n_pad + row) * 8;
    uint4 H = make_uint4(pck(hh[0],hh[1]), pck(hh[2],hh[3]), pck(hh[4],hh[5]), pck(hh[6],hh[7]));
    uint4 L = make_uint4(pck(ll[0],ll[1]), pck(ll[2],ll[3]), pck(ll[4],ll[5]), pck(ll[6],ll[7]));
    *(uint4*)(h + o) = H;
    *(uint4*)(l + o) = L;
}

// ========= conv_bw: weight matrices W[512][512] -> Bp[k/8][col][k%8] hi/lo =========
struct WcJobs { const float* src[5]; u16* h[5]; u16* l[5]; };
// grid (2, 64, 5)
__global__ __launch_bounds__(256) void conv_bw(WcJobs J)
{
    const int w = blockIdx.z;
    const float* src = J.src[w];
    const int col = blockIdx.x * 256 + threadIdx.x;
    const int kc = blockIdx.y;
    float a[8];
#pragma unroll
    for (int j = 0; j < 8; j++)
        a[j] = src[(size_t)(kc * 8 + j) * CD + col];
    u16 hh[8], ll[8];
#pragma unroll
    for (int e = 0; e < 8; e++) {
        hh[e] = f2bf(a[e]);
        ll[e] = f2bf(a[e] - bf2f(hh[e]));
    }
    size_t o = ((size_t)kc * CD + col) * 8;
    uint4 H = make_uint4(pck(hh[0],hh[1]), pck(hh[2],hh[3]), pck(hh[4],hh[5]), pck(hh[6],hh[7]));
    uint4 L = make_uint4(pck(ll[0],ll[1]), pck(ll[2],ll[3]), pck(ll[4],ll[5]), pck(ll[6],ll[7]));
    *(uint4*)(J.h[w] + o) = H;
    *(uint4*)(J.l[w] + o) = L;
}

// ========= MFMA split-bf16 GEMM: C[n x 512] = A @ B (3-product fp32 emulation) =========
// A in [64][n_pad][8] hi/lo; B in [64][512][8] hi/lo. Optional dual B (grid.y=8).
__global__ __launch_bounds__(256) void gemm_bf3(
    const u16* __restrict__ Ah, const u16* __restrict__ Al, int n, int n_pad,
    const u16* __restrict__ Bh0, const u16* __restrict__ Bl0, float* __restrict__ C0,
    const u16* __restrict__ Bh1, const u16* __restrict__ Bl1, float* __restrict__ C1)
{
    __shared__ __align__(16) u16 As_h[4][128][8];
    __shared__ __align__(16) u16 As_l[4][128][8];
    __shared__ __align__(16) u16 Bs_h[4][128][8];
    __shared__ __align__(16) u16 Bs_l[4][128][8];
    const int which = blockIdx.y >> 2;
    const u16* Bh = which ? Bh1 : Bh0;
    const u16* Bl = which ? Bl1 : Bl0;
    float* C = which ? C1 : C0;
    const int bm = blockIdx.x * 128, bn = (blockIdx.y & 3) * 128;
    const int tid = threadIdx.x, lane = tid & 63, w = tid >> 6;
    const int wm = w >> 1, wn = w & 1;
    const int l15 = lane & 15, kq = lane >> 4;

    f32x4 acc[4][4];
#pragma unroll
    for (int i = 0; i < 4; i++)
#pragma unroll
        for (int j = 0; j < 4; j++) {
            acc[i][j][0] = 0.f; acc[i][j][1] = 0.f;
            acc[i][j][2] = 0.f; acc[i][j][3] = 0.f;
        }

    for (int kt = 0; kt < 16; ++kt) {
        if (kt) __syncthreads();
        // stage 32 KB: 2048 x 16B chunks; mat: 0=Ah 1=Al 2=Bh 3=Bl
#pragma unroll
        for (int s = 0; s < 8; ++s) {
            int ci = tid + s * 256;
            int mat = ci >> 9, rem = ci & 511, kc = rem >> 7, pos = rem & 127;
            int kcg = kt * 4 + kc;
            const u16* g;
            u16* lds;
            if (mat == 0)      { g = Ah + ((size_t)kcg * n_pad + bm + pos) * 8; lds = &As_h[kc][pos][0]; }
            else if (mat == 1) { g = Al + ((size_t)kcg * n_pad + bm + pos) * 8; lds = &As_l[kc][pos][0]; }
            else if (mat == 2) { g = Bh + ((size_t)kcg * CD + bn + pos) * 8;    lds = &Bs_h[kc][pos][0]; }
            else               { g = Bl + ((size_t)kcg * CD + bn + pos) * 8;    lds = &Bs_l[kc][pos][0]; }
            *(uint4*)lds = *(const uint4*)g;
        }
        __syncthreads();
        bf16x8 ah[4], al[4], bh[4], bl[4];
#pragma unroll
        for (int f = 0; f < 4; ++f) {
            ah[f] = *(const bf16x8*)&As_h[kq][wm * 64 + f * 16 + l15][0];
            al[f] = *(const bf16x8*)&As_l[kq][wm * 64 + f * 16 + l15][0];
            bh[f] = *(const bf16x8*)&Bs_h[kq][wn * 64 + f * 16 + l15][0];
            bl[f] = *(const bf16x8*)&Bs_l[kq][wn * 64 + f * 16 + l15][0];
        }
#pragma unroll
        for (int i = 0; i < 4; ++i)
#pragma unroll
            for (int j = 0; j < 4; ++j) {
                acc[i][j] = __builtin_amdgcn_mfma_f32_16x16x32_bf16(ah[i], bh[j], acc[i][j], 0, 0, 0);
                acc[i][j] = __builtin_amdgcn_mfma_f32_16x16x32_bf16(ah[i], bl[j], acc[i][j], 0, 0, 0);
                acc[i][j] = __builtin_amdgcn_mfma_f32_16x16x32_bf16(al[i], bh[j], acc[i][j], 0, 0, 0);
            }
    }
    // C/D: col = lane&15, row = (lane>>4)*4 + reg   [m89-verified]
#pragma unroll
    for (int i = 0; i < 4; ++i) {
        int rb = bm + wm * 64 + i * 16 + kq * 4;
#pragma unroll
        for (int j = 0; j < 4; ++j) {
            int col = bn + wn * 64 + j * 16 + l15;
#pragma unroll
            for (int r = 0; r < 4; ++r) {
                int row = rb + r;
                if (row < n) C[(size_t)row * CD + col] = acc[i][j][r];
            }
        }
    }
}

// ========== dot_rows: out[r] = H[sel?sel[r]:r] . v ==========
__global__ __launch_bounds__(256) void dot_rows(
    const float* __restrict__ H, const int* __restrict__ sel,
    const float* __restrict__ v, float* __restrict__ out, int n)
{
    const int lane = threadIdx.x & 63;
    const int r = blockIdx.x * 4 + (threadIdx.x >> 6);
    if (r >= n) return;
    const int row = sel ? sel[r] : r;
    const float* h = H + (size_t)row * CD;
    float4 a0 = *(const float4*)(h + lane * 8);
    float4 a1 = *(const float4*)(h + lane * 8 + 4);
    float4 b0 = *(const float4*)(v + lane * 8);
    float4 b1 = *(const float4*)(v + lane * 8 + 4);
    float sv = a0.x * b0.x + a0.y * b0.y + a0.z * b0.z + a0.w * b0.w
             + a1.x * b1.x + a1.y * b1.y + a1.z * b1.z + a1.w * b1.w;
#pragma unroll
    for (int o = 32; o; o >>= 1) sv += __shfl_xor(sv, o, 64);
    if (lane == 0) out[r] = sv;
}

__global__ __launch_bounds__(256) void dot_rows_gather(
    const float* __restrict__ H, const int* __restrict__ rowlist,
    const int* __restrict__ nrow,
    const float* __restrict__ v, float* __restrict__ out)
{
    const int lane = threadIdx.x & 63;
    const int r = blockIdx.x * 4 + (threadIdx.x >> 6);
    if (r >= *nrow) return;
    const int row = rowlist[r];
    const float* h = H + (size_t)row * CD;
    float4 a0 = *(const float4*)(h + lane * 8);
    float4 a1 = *(const float4*)(h + lane * 8 + 4);
    float4 b0 = *(const float4*)(v + lane * 8);
    float4 b1 = *(const float4*)(v + lane * 8 + 4);
    float sv = a0.x * b0.x + a0.y * b0.y + a0.z * b0.z + a0.w * b0.w
             + a1.x * b1.x + a1.y * b1.y + a1.z * b1.z + a1.w * b1.w;
#pragma unroll
    for (int o = 32; o; o >>= 1) sv += __shfl_xor(sv, o, 64);
    if (lane == 0) out[row] = sv;
}

// ========== wa_gemv6 ==========
__global__ __launch_bounds__(256) void wa_gemv6(
    const float* __restrict__ W6, const float* __restrict__ a6, float* __restrict__ wa)
{
    const int layer = blockIdx.y;
    const int lane = threadIdx.x & 63;
    const int r = blockIdx.x * 4 + (threadIdx.x >> 6);
    const float* Wr = W6 + (size_t)layer * CDCD + (size_t)r * CD;
    const float* ah = a6 + layer * 2 * CD + CD;
    float4 a0 = *(const float4*)(Wr + lane * 8);
    float4 a1 = *(const float4*)(Wr + lane * 8 + 4);
    float4 b0 = *(const float4*)(ah + lane * 8);
    float4 b1 = *(const float4*)(ah + lane * 8 + 4);
    float sv = a0.x * b0.x + a0.y * b0.y + a0.z * b0.z + a0.w * b0.w
             + a1.x * b1.x + a1.y * b1.y + a1.z * b1.z + a1.w * b1.w;
#pragma unroll
    for (int o = 32; o; o >>= 1) sv += __shfl_xor(sv, o, 64);
    if (lane == 0) wa[layer * CD + r] = sv;
}

// ================= parallel CSR build =================
struct Csr6 {
    const int* src[6]; const int* dst[6];
    int* cnt[6]; int* off[6]; int* cur[6]; int* srcs[6];
    int nd[6]; int base[6]; int ecum[7];
};

__global__ __launch_bounds__(256) void zero_ints(int* __restrict__ p, int n)
{
    for (int i = blockIdx.x * 256 + threadIdx.x; i < n; i += gridDim.x * 256)
        p[i] = 0;
}

__global__ __launch_bounds__(256) void csr_hist(Csr6 G)
{
    const int total = G.ecum[6];
    for (int idx = blockIdx.x * 256 + threadIdx.x; idx < total; idx += gridDim.x * 256) {
        int g = 0;
        while (idx >= G.ecum[g + 1]) g++;
        int e = idx - G.ecum[g];
        atomicAdd(&G.cnt[g][G.dst[g][e] - G.base[g]], 1);
    }
}

__global__ __launch_bounds__(1024) void csr_scan(Csr6 G)
{
    __shared__ int wsum[16];
    const int g = blockIdx.x;
    const int tid = threadIdx.x, lane = tid & 63, wid = tid >> 6;
    const int n = G.nd[g];
    int* cnt = G.cnt[g];
    int* off = G.off[g];
    int* cur = G.cur[g];

    int running = 0;
    for (int base = 0; base < n; base += 1024) {
        int idx = base + tid;
        int v0 = (idx < n) ? cnt[idx] : 0;
        int v = v0;
#pragma unroll
        for (int dlt = 1; dlt < 64; dlt <<= 1) {
            int t = __shfl_up(v, dlt, 64);
            if (lane >= dlt) v += t;
        }
        if (lane == 63) wsum[wid] = v;
        __syncthreads();
        if (wid == 0) {
            int wv = (lane < 16) ? wsum[lane] : 0;
#pragma unroll
            for (int dlt = 1; dlt < 16; dlt <<= 1) {
                int t = __shfl_up(wv, dlt, 64);
                if (lane >= dlt) wv += t;
            }
            if (lane < 16) wsum[lane] = wv;
        }
        __syncthreads();
        int wprefix = (wid > 0) ? wsum[wid - 1] : 0;
        int chunk_total = wsum[15];
        int excl = running + wprefix + (v - v0);
        if (idx < n) { off[idx] = excl; cur[idx] = excl; }
        running += chunk_total;
        __syncthreads();
    }
    if (tid == 0) off[n] = running;
}

__global__ __launch_bounds__(256) void csr_scatter(Csr6 G)
{
    const int total = G.ecum[6];
    for (int idx = blockIdx.x * 256 + threadIdx.x; idx < total; idx += gridDim.x * 256) {
        int g = 0;
        while (idx >= G.ecum[g + 1]) g++;
        int e = idx - G.ecum[g];
        int dl = G.dst[g][e] - G.base[g];
        int pos = atomicAdd(&G.cur[g][dl], 1);
        G.srcs[g][pos] = G.src[g][e];
    }
}

__global__ void mark_qsel(const int* __restrict__ qid, int* __restrict__ qsel)
{
    qsel[qid[threadIdx.x]] = 1;
}

__global__ __launch_bounds__(256) void mark_l5(
    const int* __restrict__ esrc, const int* __restrict__ edst, int ne,
    const int* __restrict__ qsel, int* __restrict__ umark,
    int* __restrict__ list, int* __restrict__ nlist)
{
    for (int e = blockIdx.x * 256 + threadIdx.x; e < ne; e += gridDim.x * 256) {
        if (qsel[edst[e]]) {
            int u = esrc[e] - QN;
            if (atomicExch(&umark[u], 1) == 0)
                list[atomicAdd(nlist, 1)] = u;
        }
    }
}

// ================= GAT aggregate =================
__global__ __launch_bounds__(256) void gat_aggregate(
    const int* __restrict__ off, const int* __restrict__ srcs, int src_base,
    const int* __restrict__ sel,
    const float* __restrict__ z, const float* __restrict__ s,
    const float* __restrict__ dvals,
    const float* __restrict__ base, float* __restrict__ out)
{
    const int b = blockIdx.x;
    const int node = sel ? sel[b] : b;
    const int tid = threadIdx.x;
    const int lane = tid & 63, wid = tid >> 6;
    const int beg = off[node], end = off[node + 1];

    float2 bacc = base ? *(const float2*)(base + (size_t)node * CD + tid * 2)
                       : make_float2(0.f, 0.f);
    if (beg == end) {
        *(float2*)(out + (size_t)b * CD + tid * 2) = bacc;
        return;
    }
    const float dd = dvals[b];

    float m = -1e30f, den = 0.f;
    for (int e = beg + tid; e < end; e += 256) {
        float sc = s[srcs[e] - src_base] + dd;
        sc = sc > 0.f ? sc : 0.01f * sc;
        if (sc > m) { den = den * __expf(m - sc) + 1.f; m = sc; }
        else den += __expf(sc - m);
    }
#pragma unroll
    for (int o = 32; o; o >>= 1) {
        float om = __shfl_xor(m, o, 64);
        float od = __shfl_xor(den, o, 64);
        float nm = fmaxf(m, om);
        den = den * __expf(m - nm) + od * __expf(om - nm);
        m = nm;
    }
    __shared__ float wm[4], wd[4];
    __shared__ float alpha_s[256];
    __shared__ int   src_s[256];
    if (lane == 0) { wm[wid] = m; wd[wid] = den; }
    __syncthreads();
    float M = fmaxf(fmaxf(wm[0], wm[1]), fmaxf(wm[2], wm[3]));
    float Dn = wd[0] * __expf(wm[0] - M) + wd[1] * __expf(wm[1] - M)
             + wd[2] * __expf(wm[2] - M) + wd[3] * __expf(wm[3] - M);
    float invD = 1.f / Dn;

    for (int c0 = beg; c0 < end; c0 += 256) {
        int e = c0 + tid;
        float al = 0.f; int sr = 0;
        if (e < end) {
            sr = srcs[e] - src_base;
            float sc = s[sr] + dd;
            sc = sc > 0.f ? sc : 0.01f * sc;
            al = __expf(sc - M) * invD;
        }
        __syncthreads();
        alpha_s[tid] = al; src_s[tid] = sr;
        __syncthreads();
        int cc = min(256, end - c0);
        for (int jj = 0; jj < cc; jj++) {
            const float* zr = z + (size_t)src_s[jj] * CD;
            float a = alpha_s[jj];
            float2 v = *(const float2*)(zr + tid * 2);
            bacc.x = fmaf(a, v.x, bacc.x);
            bacc.y = fmaf(a, v.y, bacc.y);
        }
    }
    *(float2*)(out + (size_t)b * CD + tid * 2) = bacc;
}

// ================= attention fuse kn =================
__global__ __launch_bounds__(256) void fuse_kn(
    const float* __restrict__ kn, const float* __restrict__ kd,
    const float* __restrict__ ku, const float* __restrict__ Dm,
    const float* __restrict__ aw, const float* __restrict__ ab, float* __restrict__ out)
{
    const int i = blockIdx.x, tid = threadIdx.x;
    const int lane = tid & 63, wid = tid >> 6;
    const size_t ro = (size_t)i * CD + tid * 2;
    const int c = tid * 2;
    float2 vkn = *(const float2*)(kn + ro);
    float2 v1  = *(const float2*)(kd + ro);
    float2 v2  = *(const float2*)(ku + ro);
    float2 v3  = *(const float2*)(Dm + ro);
    float p1 = vkn.x*aw[c]      + vkn.y*aw[c+1]      + v1.x*aw[CD+c]      + v1.y*aw[CD+c+1];
    float p2 = vkn.x*aw[1024+c] + vkn.y*aw[1024+c+1] + v2.x*aw[1024+CD+c] + v2.y*aw[1024+CD+c+1];
    float p3 = vkn.x*aw[2048+c] + vkn.y*aw[2048+c+1] + v3.x*aw[2048+CD+c] + v3.y*aw[2048+CD+c+1];
#pragma unroll
    for (int o = 32; o; o >>= 1) {
        p1 += __shfl_xor(p1, o, 64); p2 += __shfl_xor(p2, o, 64); p3 += __shfl_xor(p3, o, 64);
    }
    __shared__ float r1[4], r2[4], r3[4];
    if (lane == 0) { r1[wid] = p1; r2[wid] = p2; r3[wid] = p3; }
    __syncthreads();
    float s1 = r1[0]+r1[1]+r1[2]+r1[3] + ab[0];
    float s2 = r2[0]+r2[1]+r2[2]+r2[3] + ab[1];
    float s3 = r3[0]+r3[1]+r3[2]+r3[3] + ab[2];
    float mm = fmaxf(s1, fmaxf(s2, s3));
    float e1 = __expf(s1-mm), e2 = __expf(s2-mm), e3 = __expf(s3-mm);
    float inv = 1.f / (e1 + e2 + e3);
    float w1 = e1*inv, w2 = e2*inv, w3 = e3*inv;
    float2 o_;
    o_.x = vkn.x + w1*v1.x + w2*v2.x + w3*v3.x;
    o_.y = vkn.y + w1*v1.y + w2*v2.y + w3*v3.y;
    *(float2*)(out + ro) = o_;
}

// ================= attention fuse ex =================
__global__ __launch_bounds__(256) void fuse_ex(
    const float* __restrict__ ex, const int* __restrict__ sel,
    const float* __restrict__ Bq, const float* __restrict__ Cq,
    const float* __restrict__ aw, const float* __restrict__ ab, float* __restrict__ out)
{
    const int i = blockIdx.x, tid = threadIdx.x;
    const int lane = tid & 63, wid = tid >> 6;
    const int exrow = sel ? sel[i] : i;
    const size_t eo = (size_t)exrow * CD + tid * 2;
    const size_t ro = (size_t)i * CD + tid * 2;
    const int c = tid * 2;
    float2 ve = *(const float2*)(ex + eo);
    float2 vb = *(const float2*)(Bq + ro);
    float2 vc = *(const float2*)(Cq + ro);
    const float* a3 = aw + 3 * 2 * CD;
    const float* a4 = aw + 4 * 2 * CD;
    float p1 = ve.x*a3[c] + ve.y*a3[c+1] + vb.x*a3[CD+c] + vb.y*a3[CD+c+1];
    float p2 = ve.x*a4[c] + ve.y*a4[c+1] + vc.x*a4[CD+c] + vc.y*a4[CD+c+1];
#pragma unroll
    for (int o = 32; o; o >>= 1) { p1 += __shfl_xor(p1, o, 64); p2 += __shfl_xor(p2, o, 64); }
    __shared__ float r1[4], r2[4];
    if (lane == 0) { r1[wid] = p1; r2[wid] = p2; }
    __syncthreads();
    float t1 = r1[0]+r1[1]+r1[2]+r1[3] + ab[3];
    float t2 = r2[0]+r2[1]+r2[2]+r2[3] + ab[4];
    float mm = fmaxf(t1, t2);
    float e1 = __expf(t1-mm), e2 = __expf(t2-mm);
    float inv = 1.f / (e1 + e2);
    float w1 = e1*inv, w2 = e2*inv;
    float2 o_;
    o_.x = ve.x + w1*vb.x + w2*vc.x;
    o_.y = ve.y + w1*vb.y + w2*vc.y;
    *(float2*)(out + ro) = o_;
}

// ===== final prediction (q_table-sparse) =====
__global__ __launch_bounds__(256) void final_pred(
    const float* __restrict__ sP, const float* __restrict__ kP,
    const float* __restrict__ dP, const float* __restrict__ kD,
    const float* __restrict__ W3, const float* __restrict__ b3,
    const float* __restrict__ q_table, const int* __restrict__ qid,
    float* __restrict__ out)
{
    const int b = blockIdx.x;
    const int tid = threadIdx.x, lane = tid & 63, wid = tid >> 6;
    __shared__ int   sidx[CD];
    __shared__ float sqv[CD];
    __shared__ int   snn;
    __shared__ float scnt[4], sacc[4];
    if (tid == 0) snn = 0;
    __syncthreads();
    const float* qrow = q_table + (size_t)qid[b] * CD;
    float cnt = 0.f;
    for (int i = tid; i < CD; i += 256) {
        float qv = qrow[i];
        if (qv != 0.f) {
            int p = atomicAdd(&snn, 1);
            sidx[p] = i; sqv[p] = qv;
            cnt += qv;
        }
    }
#pragma unroll
    for (int o = 32; o; o >>= 1) cnt += __shfl_xor(cnt, o, 64);
    if (lane == 0) scnt[wid] = cnt;
    __syncthreads();
    const int nn = snn;
    const float bb = b3[0];
    const float* sPr = sP + (size_t)b * CD;
    const float* dPr = dP + (size_t)b * CD;
    float acc = 0.f;
    for (int t = wid; t < nn; t += 4) {
        const int i = sidx[t];
        const float* kPr = kP + (size_t)i * CD;
        const float* kDr = kD + (size_t)i * CD;
        float o = 0.f;
#pragma unroll
        for (int p = 0; p < 8; p++) {
            int j = lane + (p << 6);
            float pv = sPr[j] + kPr[j];
            float dv = dPr[j] + kDr[j];
            float s1 = 1.f / (1.f + __expf(-pv));
            float s2 = 1.f / (1.f + __expf(-dv));
            o += (s1 - s2) * W3[j];
        }
#pragma unroll
        for (int ofs = 32; ofs; ofs >>= 1) o += __shfl_xor(o, ofs, 64);
        if (lane == 0) acc += sqv[t] / (1.f + __expf(-(o + bb)));
    }
    if (lane == 0) sacc[wid] = acc;
    __syncthreads();
    if (tid == 0)
        out[b] = (sacc[0] + sacc[1] + sacc[2] + sacc[3])
               / (scnt[0] + scnt[1] + scnt[2] + scnt[3]);
}

// ================= host orchestration =================
#define EXPAD 8192
#define STUPAD 20224

extern "C" void kernel_launch(void* const* d_in, const int* in_sizes, int n_in,
                              void* d_out, int out_size, void* d_ws, size_t ws_size,
                              hipStream_t stream)
{
    const int*   user_id      = (const int*)d_in[0];
    const int*   question_id  = (const int*)d_in[1];
    const float* q_table      = (const float*)d_in[2];
    const int*   e_dir        = (const int*)d_in[3];
    const int*   e_und        = (const int*)d_in[4];
    const int*   e_ke         = (const int*)d_in[5];
    const int*   e_ek         = (const int*)d_in[6];
    const int*   e_ue         = (const int*)d_in[7];
    const int*   e_eu         = (const int*)d_in[8];
    const float* user_emb     = (const float*)d_in[9];
    const float* question_emb = (const float*)d_in[10];
    const float* concept_emb  = (const float*)d_in[11];
    const float* gat_W        = (const float*)d_in[12];
    const float* gat_a        = (const float*)d_in[13];
    const float* attn_w       = (const float*)d_in[14];
    const float* attn_b       = (const float*)d_in[15];
    const float* W1           = (const float*)d_in[16];
    const float* W2           = (const float*)d_in[17];
    const float* W3           = (const float*)d_in[18];
    const float* b3           = (const float*)d_in[19];
    float* out = (float*)d_out;

    char* wptr = (char*)d_ws;
    auto alloc = [&](size_t bytes) -> void* {
        void* p = (void*)wptr;
        wptr += (bytes + 255) & ~(size_t)255;
        return p;
    };

    float* zone = (float*)alloc((size_t)UN * CD * 4);
    float* z2 = zone;
    float* z4 = zone + (size_t)QN * CD;
    float* z5 = zone;
    float* z0 = (float*)alloc((size_t)CD * CD * 4);
    float* z1 = (float*)alloc((size_t)CD * CD * 4);
    float* z3 = (float*)alloc((size_t)CD * CD * 4);

    float* s0 = (float*)alloc((size_t)CD * 4);
    float* s1 = (float*)alloc((size_t)CD * 4);
    float* s2 = (float*)alloc((size_t)QN * 4);
    float* s3 = (float*)alloc((size_t)CD * 4);
    float* s4 = (float*)alloc((size_t)QN * 4);
    float* s5 = (float*)alloc((size_t)UN * 4);
    float* dv0 = (float*)alloc((size_t)CD * 4);
    float* dv1 = (float*)alloc((size_t)CD * 4);
    float* dv2 = (float*)alloc((size_t)CD * 4);
    float* dv3 = (float*)alloc((size_t)QN * 4);
    float* dv4 = (float*)alloc((size_t)UN * 4);
    float* dv5 = (float*)alloc((size_t)QN * 4);
    float* wa  = (float*)alloc((size_t)6 * CD * 4);

    float* kn1  = (float*)alloc((size_t)CD * CD * 4);
    float* ex1  = (float*)alloc((size_t)QN * CD * 4);
    float* stu1 = (float*)alloc((size_t)UN * CD * 4);
    float* kn2  = (float*)alloc((size_t)CD * CD * 4);
    float* kdir = (float*)alloc((size_t)CD * CD * 4);
    float* kund = (float*)alloc((size_t)CD * CD * 4);
    float* Dm   = (float*)alloc((size_t)CD * CD * 4);
    float* Bq   = (float*)alloc((size_t)QN * CD * 4);
    float* Cq   = (float*)alloc((size_t)QN * CD * 4);
    float* eb   = (float*)alloc((size_t)BATCHN * CD * 4);
    float* sb   = (float*)alloc((size_t)BATCHN * CD * 4);
    float* sP   = (float*)alloc((size_t)BATCHN * CD * 4);
    float* dP   = (float*)alloc((size_t)BATCHN * CD * 4);
    float* kP   = (float*)alloc((size_t)CD * CD * 4);
    float* kD   = (float*)alloc((size_t)CD * CD * 4);

    // split-bf16 buffers
    u16* expH  = (u16*)alloc((size_t)64 * EXPAD * 8 * 2);
    u16* expL  = (u16*)alloc((size_t)64 * EXPAD * 8 * 2);
    u16* stupH = (u16*)alloc((size_t)64 * STUPAD * 8 * 2);
    u16* stupL = (u16*)alloc((size_t)64 * STUPAD * 8 * 2);
    u16* BpH[5]; u16* BpL[5];
    for (int i = 0; i < 5; i++) {
        BpH[i] = (u16*)alloc((size_t)64 * CD * 8 * 2);
        BpL[i] = (u16*)alloc((size_t)64 * CD * 8 * 2);
    }

    static const int g_ne[6]   = {4096, 8192, 40000, 40000, 100000, 100000};
    static const int g_nd[6]   = {512, 512, 512, QN, UN, QN};
    static const int g_base[6] = {0, 0, QN, 0, QN, 0};
    const int* g_edges[6] = {e_dir, e_und, e_ke, e_ek, e_ue, e_eu};

    int cnt_total = 0;
    for (int g = 0; g < 6; g++) cnt_total += g_nd[g];
    int* zbase = (int*)alloc((size_t)(cnt_total + QN + UN + 1) * 4);
    int* cnt6[6];
    {
        int o = 0;
        for (int g = 0; g < 6; g++) { cnt6[g] = zbase + o; o += g_nd[g]; }
    }
    int* qsel  = zbase + cnt_total;
    int* umark = qsel + QN;
    int* nlist = umark + UN;
    const int ZTOT = cnt_total + QN + UN + 1;

    int* cur6 = (int*)alloc((size_t)cnt_total * 4);
    int* list = (int*)alloc((size_t)UN * 4);
    int* off[6]; int* srcs[6];
    for (int g = 0; g < 6; g++) {
        off[g]  = (int*)alloc((size_t)(g_nd[g] + 1) * 4);
        srcs[g] = (int*)alloc((size_t)g_ne[g] * 4);
    }

    Csr6 G;
    {
        int o = 0, ec = 0;
        for (int g = 0; g < 6; g++) {
            G.src[g] = g_edges[g];
            G.dst[g] = g_edges[g] + g_ne[g];
            G.cnt[g] = cnt6[g];
            G.off[g] = off[g];
            G.cur[g] = cur6 + o;
            G.srcs[g] = srcs[g];
            G.nd[g] = g_nd[g];
            G.base[g] = g_base[g];
            G.ecum[g] = ec;
            o += g_nd[g]; ec += g_ne[g];
        }
        G.ecum[6] = ec;
    }

    zero_ints<<<128, 256, 0, stream>>>(zbase, ZTOT);
    csr_hist<<<512, 256, 0, stream>>>(G);
    csr_scan<<<6, 1024, 0, stream>>>(G);
    csr_scatter<<<512, 256, 0, stream>>>(G);
    mark_qsel<<<1, BATCHN, 0, stream>>>(question_id, qsel);
    mark_l5<<<200, 256, 0, stream>>>(e_eu, e_eu + 100000, 100000, qsel, umark, list, nlist);

    // pre-convert the 5 weight matrices used by MFMA GEMMs: f0:{l2,l4,l5}, f1:{l2,l4}
    {
        WcJobs wj;
        const int fl[5][2] = {{0,2},{0,4},{0,5},{1,2},{1,4}};
        for (int i = 0; i < 5; i++) {
            wj.src[i] = gat_W + (size_t)(fl[i][0] * 6 + fl[i][1]) * CDCD;
            wj.h[i] = BpH[i]; wj.l[i] = BpL[i];
        }
        conv_bw<<<dim3(2, 64, 5), 256, 0, stream>>>(wj);
    }

    auto gemm = [&](const float* A, int n, const float* B0, float* C0,
                    const float* B1, float* C1) {
        dim3 g((n + GBM - 1) / GBM, B1 ? 8 : 4);
        gemm_f32<<<g, 256, 0, stream>>>(A, n, B0, C0, B1, C1);
    };
    auto dots = [&](const float* H, const int* sel, const float* v, float* o, int n) {
        dot_rows<<<(n + 3) / 4, 256, 0, stream>>>(H, sel, v, o, n);
    };
    auto agg = [&](int g, int src_base, const int* sel, const float* z, const float* s,
                   const float* dv, const float* base, float* o, int nblk) {
        gat_aggregate<<<nblk, 256, 0, stream>>>(off[g], srcs[g], src_base, sel,
                                                z, s, dv, base, o);
    };

    auto run_fusion = [&](int f, const float* kn, const float* ex, const float* stu,
                          const int* selq, const int* selu, int nd3, int nd4, int nd5,
                          float* kn_o, float* ex_o, float* stu_o) {
        const float* Wf  = gat_W  + (size_t)f * 6 * CDCD;
        const float* af  = gat_a  + (size_t)f * 6 * 2 * CD;
        const float* awf = attn_w + (size_t)f * 5 * 2 * CD;
        const float* abf = attn_b + (size_t)f * 5;
        const int bp = f * 3;   // Bp base index: f0 -> 0,1,2 ; f1 -> 3,4

        // convert activations feeding the MFMA GEMMs
        conv_a<<<dim3(EXPAD / 256, 64), 256, 0, stream>>>(ex, expH, expL, QN);
        if (!selq)
            conv_a<<<dim3(STUPAD / 256, 64), 256, 0, stream>>>(stu, stupH, stupL, UN);

        wa_gemv6<<<dim3(128, 6), 256, 0, stream>>>(Wf, af, wa);

        // l0 + l1 (A = kn, fp32 dual)
        gemm(kn, CD, Wf + 0 * CDCD, z0, Wf + 1 * CDCD, z1);
        dots(z0, nullptr, af + 0 * 2 * CD, s0, CD);
        dots(z1, nullptr, af + 1 * 2 * CD, s1, CD);
        dots(kn, nullptr, wa + 0 * CD, dv0, CD);
        dots(kn, nullptr, wa + 1 * CD, dv1, CD);
        agg(0, 0, nullptr, z0, s0, dv0, nullptr, kdir, CD);
        agg(1, 0, nullptr, z1, s1, dv1, nullptr, kund, CD);

        // l2 + l4 (A = ex, MFMA split-bf16 dual)
        gemm_bf3<<<dim3((QN + 127) / 128, 8), 256, 0, stream>>>(
            expH, expL, QN, EXPAD,
            BpH[bp + 0], BpL[bp + 0], z2,
            BpH[bp + 1], BpL[bp + 1], z4);
        dots(z2, nullptr, af + 2 * 2 * CD, s2, QN);
        dots(kn, nullptr, wa + 2 * CD, dv2, CD);
        agg(2, 0, nullptr, z2, s2, dv2, nullptr, Dm, CD);

        // l3 (A = kn, fp32)
        gemm(kn, CD, Wf + 3 * CDCD, z3, nullptr, nullptr);
        dots(z3, nullptr, af + 3 * 2 * CD, s3, CD);
        dots(ex, selq, wa + 3 * CD, dv3, nd3);
        agg(3, QN, selq, z3, s3, dv3, nullptr, Bq, nd3);

        // l4 aggregation
        dots(z4, nullptr, af + 4 * 2 * CD, s4, QN);
        dots(stu, selu, wa + 4 * CD, dv4, nd4);
        agg(4, 0, selu, z4, s4, dv4, stu, stu_o, nd4);

        // l5 (A = stu) — z5 aliases zone, safe only after l2/l4 aggregates done
        if (!selq) {
            gemm_bf3<<<dim3((UN + 127) / 128, 4), 256, 0, stream>>>(
                stupH, stupL, UN, STUPAD,
                BpH[bp + 2], BpL[bp + 2], z5,
                nullptr, nullptr, nullptr);
            dots(z5, nullptr, af + 5 * 2 * CD, s5, UN);
        } else {
            dim3 gg((UN + GBM - 1) / GBM, 4);
            gemm_f32_gather<<<gg, 256, 0, stream>>>(stu, list, nlist, Wf + 5 * CDCD, z5);
            dot_rows_gather<<<(UN + 3) / 4, 256, 0, stream>>>(z5, list, nlist,
                                                              af + 5 * 2 * CD, s5);
        }
        dots(ex, selq, wa + 5 * CD, dv5, nd5);
        agg(5, QN, selq, z5, s5, dv5, nullptr, Cq, nd5);

        fuse_kn<<<CD, 256, 0, stream>>>(kn, kdir, kund, Dm, awf, abf, kn_o);
        fuse_ex<<<nd3, 256, 0, stream>>>(ex, selq, Bq, Cq, awf, abf, ex_o);
    };

    run_fusion(0, concept_emb, question_emb, user_emb,
               nullptr, nullptr, QN, UN, QN, kn1, ex1, stu1);
    run_fusion(1, kn1, ex1, stu1,
               question_id, user_id, BATCHN, BATCHN, BATCHN, kn2, eb, sb);

    // prediction head (small, fp32)
    gemm(sb, BATCHN, W1, sP, nullptr, nullptr);
    gemm(eb, BATCHN, W2, dP, nullptr, nullptr);
    gemm(kn2, CD, W1 + (size_t)CDCD, kP, W2 + (size_t)CDCD, kD);
    final_pred<<<BATCHN, 256, 0, stream>>>(sP, kP, dP, kD, W3, b3, q_table, question_id, out);
}

// Round 7
// 880.910 us; speedup vs baseline: 2.2050x; 1.4356x over previous
//
#include <hip/hip_runtime.h>
#include <math.h>

#define CD 512
#define CDCD (CD * CD)
#define QN 8000
#define UN 20000
#define BATCHN 128

typedef unsigned short u16;
typedef unsigned int u32;
typedef __attribute__((ext_vector_type(8))) __bf16 bf16x8;
typedef __attribute__((ext_vector_type(4))) float f32x4;

static __device__ __forceinline__ u16 f2bf(float x) {
    u32 u = __float_as_uint(x);
    return (u16)((u + 0x7fff + ((u >> 16) & 1)) >> 16);
}
static __device__ __forceinline__ float bf2f(u16 h) {
    return __uint_as_float(((u32)h) << 16);
}
static __device__ __forceinline__ u32 pck(u16 a, u16 b) {
    return (u32)a | ((u32)b << 16);
}

// ============ small-tile fp32 GEMM: 32x64 tile, optional rowlist gather/scatter ======
// grid.x covers rows/32 (early-exit on device count if nrow); grid.y = 8 (single) or
// 16 (dual B: y>=8 -> B1/C1). C[row] = A[rowlist?rowlist[row]:row] @ B.
#define SBM 32
#define SBN 64
#define SBK 32

__global__ __launch_bounds__(256) void gemm_f32_s(
    const float* __restrict__ A, int nfix,
    const int* __restrict__ rowlist, const int* __restrict__ nrow,
    const float* __restrict__ B0, float* __restrict__ C0,
    const float* __restrict__ B1, float* __restrict__ C1)
{
    const int n = nrow ? *nrow : nfix;
    const int bm = blockIdx.x * SBM;
    if (bm >= n) return;
    __shared__ __align__(16) float As[SBM][SBK + 4];
    __shared__ __align__(16) float Bs[SBK][SBN];
    const int which = blockIdx.y >> 3;
    const float* __restrict__ B = which ? B1 : B0;
    float* __restrict__ C = which ? C1 : C0;
    const int bn = (blockIdx.y & 7) * SBN;
    const int tid = threadIdx.x;
    const int ty = tid >> 3, tx = tid & 7;
    const int am = tid >> 3, ak = (tid & 7) * 4;
    const int bk = tid >> 3, bc = (tid & 7) * 8;
    const int gr = bm + am;
    const bool aok = gr < n;
    const int arow = aok ? (rowlist ? rowlist[gr] : gr) : 0;
    const float* Arow = A + (size_t)arow * CD;

    float acc[8];
#pragma unroll
    for (int j = 0; j < 8; j++) acc[j] = 0.f;

    for (int k0 = 0; k0 < CD; k0 += SBK) {
        float4 av = make_float4(0.f, 0.f, 0.f, 0.f);
        if (aok) av = *(const float4*)(Arow + k0 + ak);
        float4 bv0 = *(const float4*)(B + (size_t)(k0 + bk) * CD + bn + bc);
        float4 bv1 = *(const float4*)(B + (size_t)(k0 + bk) * CD + bn + bc + 4);
        __syncthreads();
        *(float4*)&As[am][ak] = av;
        *(float4*)&Bs[bk][bc] = bv0;
        *(float4*)&Bs[bk][bc + 4] = bv1;
        __syncthreads();
#pragma unroll
        for (int kk = 0; kk < SBK; kk++) {
            float a = As[ty][kk];
            float4 b0 = *(const float4*)&Bs[kk][tx * 8];
            float4 b1 = *(const float4*)&Bs[kk][tx * 8 + 4];
            acc[0] = fmaf(a, b0.x, acc[0]); acc[1] = fmaf(a, b0.y, acc[1]);
            acc[2] = fmaf(a, b0.z, acc[2]); acc[3] = fmaf(a, b0.w, acc[3]);
            acc[4] = fmaf(a, b1.x, acc[4]); acc[5] = fmaf(a, b1.y, acc[5]);
            acc[6] = fmaf(a, b1.z, acc[6]); acc[7] = fmaf(a, b1.w, acc[7]);
        }
    }
    if (gr < n) {
        int orow = rowlist ? rowlist[gr] : gr;
        // note: per-thread row == am == ty
        *(float4*)(C + (size_t)orow * CD + bn + tx * 8) =
            make_float4(acc[0], acc[1], acc[2], acc[3]);
        *(float4*)(C + (size_t)orow * CD + bn + tx * 8 + 4) =
            make_float4(acc[4], acc[5], acc[6], acc[7]);
    }
}

// ========= conv_a: fp32 activations -> split bf16 hi/lo, layout [64][n_pad][8] =========
__global__ __launch_bounds__(256) void conv_a(
    const float* __restrict__ src, u16* __restrict__ h, u16* __restrict__ l, int n)
{
    const int row = blockIdx.x * 256 + threadIdx.x;
    const int kc = blockIdx.y;
    const int n_pad = gridDim.x * 256;
    float4 v0 = make_float4(0.f, 0.f, 0.f, 0.f), v1 = v0;
    if (row < n) {
        v0 = *(const float4*)(src + (size_t)row * CD + kc * 8);
        v1 = *(const float4*)(src + (size_t)row * CD + kc * 8 + 4);
    }
    float a[8] = {v0.x, v0.y, v0.z, v0.w, v1.x, v1.y, v1.z, v1.w};
    u16 hh[8], ll[8];
#pragma unroll
    for (int e = 0; e < 8; e++) {
        hh[e] = f2bf(a[e]);
        ll[e] = f2bf(a[e] - bf2f(hh[e]));
    }
    size_t o = ((size_t)kc * n_pad + row) * 8;
    uint4 H = make_uint4(pck(hh[0],hh[1]), pck(hh[2],hh[3]), pck(hh[4],hh[5]), pck(hh[6],hh[7]));
    uint4 L = make_uint4(pck(ll[0],ll[1]), pck(ll[2],ll[3]), pck(ll[4],ll[5]), pck(ll[6],ll[7]));
    *(uint4*)(h + o) = H;
    *(uint4*)(l + o) = L;
}

// ========= conv_bw: weight matrices W[512][512] -> Bp[k/8][col][k%8] hi/lo =========
struct WcJobs { const float* src[5]; u16* h[5]; u16* l[5]; };
__global__ __launch_bounds__(256) void conv_bw(WcJobs J)
{
    const int w = blockIdx.z;
    const float* src = J.src[w];
    const int col = blockIdx.x * 256 + threadIdx.x;
    const int kc = blockIdx.y;
    float a[8];
#pragma unroll
    for (int j = 0; j < 8; j++)
        a[j] = src[(size_t)(kc * 8 + j) * CD + col];
    u16 hh[8], ll[8];
#pragma unroll
    for (int e = 0; e < 8; e++) {
        hh[e] = f2bf(a[e]);
        ll[e] = f2bf(a[e] - bf2f(hh[e]));
    }
    size_t o = ((size_t)kc * CD + col) * 8;
    uint4 H = make_uint4(pck(hh[0],hh[1]), pck(hh[2],hh[3]), pck(hh[4],hh[5]), pck(hh[6],hh[7]));
    uint4 L = make_uint4(pck(ll[0],ll[1]), pck(ll[2],ll[3]), pck(ll[4],ll[5]), pck(ll[6],ll[7]));
    *(uint4*)(J.h[w] + o) = H;
    *(uint4*)(J.l[w] + o) = L;
}

// ========= MFMA split-bf16 GEMM (3-product fp32 emulation), 128x128 tile =========
__global__ __launch_bounds__(256) void gemm_bf3(
    const u16* __restrict__ Ah, const u16* __restrict__ Al, int n, int n_pad,
    const u16* __restrict__ Bh0, const u16* __restrict__ Bl0, float* __restrict__ C0,
    const u16* __restrict__ Bh1, const u16* __restrict__ Bl1, float* __restrict__ C1)
{
    __shared__ __align__(16) u16 As_h[4][128][8];
    __shared__ __align__(16) u16 As_l[4][128][8];
    __shared__ __align__(16) u16 Bs_h[4][128][8];
    __shared__ __align__(16) u16 Bs_l[4][128][8];
    const int which = blockIdx.y >> 2;
    const u16* Bh = which ? Bh1 : Bh0;
    const u16* Bl = which ? Bl1 : Bl0;
    float* C = which ? C1 : C0;
    const int bm = blockIdx.x * 128, bn = (blockIdx.y & 3) * 128;
    const int tid = threadIdx.x, lane = tid & 63, w = tid >> 6;
    const int wm = w >> 1, wn = w & 1;
    const int l15 = lane & 15, kq = lane >> 4;

    f32x4 acc[4][4];
#pragma unroll
    for (int i = 0; i < 4; i++)
#pragma unroll
        for (int j = 0; j < 4; j++) {
            acc[i][j][0] = 0.f; acc[i][j][1] = 0.f;
            acc[i][j][2] = 0.f; acc[i][j][3] = 0.f;
        }

    for (int kt = 0; kt < 16; ++kt) {
        if (kt) __syncthreads();
#pragma unroll
        for (int s = 0; s < 8; ++s) {
            int ci = tid + s * 256;
            int mat = ci >> 9, rem = ci & 511, kc = rem >> 7, pos = rem & 127;
            int kcg = kt * 4 + kc;
            const u16* g;
            u16* lds;
            if (mat == 0)      { g = Ah + ((size_t)kcg * n_pad + bm + pos) * 8; lds = &As_h[kc][pos][0]; }
            else if (mat == 1) { g = Al + ((size_t)kcg * n_pad + bm + pos) * 8; lds = &As_l[kc][pos][0]; }
            else if (mat == 2) { g = Bh + ((size_t)kcg * CD + bn + pos) * 8;    lds = &Bs_h[kc][pos][0]; }
            else               { g = Bl + ((size_t)kcg * CD + bn + pos) * 8;    lds = &Bs_l[kc][pos][0]; }
            *(uint4*)lds = *(const uint4*)g;
        }
        __syncthreads();
        bf16x8 ah[4], al[4], bh[4], bl[4];
#pragma unroll
        for (int f = 0; f < 4; ++f) {
            ah[f] = *(const bf16x8*)&As_h[kq][wm * 64 + f * 16 + l15][0];
            al[f] = *(const bf16x8*)&As_l[kq][wm * 64 + f * 16 + l15][0];
            bh[f] = *(const bf16x8*)&Bs_h[kq][wn * 64 + f * 16 + l15][0];
            bl[f] = *(const bf16x8*)&Bs_l[kq][wn * 64 + f * 16 + l15][0];
        }
#pragma unroll
        for (int i = 0; i < 4; ++i)
#pragma unroll
            for (int j = 0; j < 4; ++j) {
                acc[i][j] = __builtin_amdgcn_mfma_f32_16x16x32_bf16(ah[i], bh[j], acc[i][j], 0, 0, 0);
                acc[i][j] = __builtin_amdgcn_mfma_f32_16x16x32_bf16(ah[i], bl[j], acc[i][j], 0, 0, 0);
                acc[i][j] = __builtin_amdgcn_mfma_f32_16x16x32_bf16(al[i], bh[j], acc[i][j], 0, 0, 0);
            }
    }
#pragma unroll
    for (int i = 0; i < 4; ++i) {
        int rb = bm + wm * 64 + i * 16 + kq * 4;
#pragma unroll
        for (int j = 0; j < 4; ++j) {
            int col = bn + wn * 64 + j * 16 + l15;
#pragma unroll
            for (int r = 0; r < 4; ++r) {
                int row = rb + r;
                if (row < n) C[(size_t)row * CD + col] = acc[i][j][r];
            }
        }
    }
}

// ========== dot_rows: out[r] = H[sel?sel[r]:r] . v ==========
__global__ __launch_bounds__(256) void dot_rows(
    const float* __restrict__ H, const int* __restrict__ sel,
    const float* __restrict__ v, float* __restrict__ out, int n)
{
    const int lane = threadIdx.x & 63;
    const int r = blockIdx.x * 4 + (threadIdx.x >> 6);
    if (r >= n) return;
    const int row = sel ? sel[r] : r;
    const float* h = H + (size_t)row * CD;
    float4 a0 = *(const float4*)(h + lane * 8);
    float4 a1 = *(const float4*)(h + lane * 8 + 4);
    float4 b0 = *(const float4*)(v + lane * 8);
    float4 b1 = *(const float4*)(v + lane * 8 + 4);
    float sv = a0.x * b0.x + a0.y * b0.y + a0.z * b0.z + a0.w * b0.w
             + a1.x * b1.x + a1.y * b1.y + a1.z * b1.z + a1.w * b1.w;
#pragma unroll
    for (int o = 32; o; o >>= 1) sv += __shfl_xor(sv, o, 64);
    if (lane == 0) out[r] = sv;
}

// === dot over device row list, scatter result to out[rowlist[r]] ===
__global__ __launch_bounds__(256) void dot_rows_gather(
    const float* __restrict__ H, const int* __restrict__ rowlist,
    const int* __restrict__ nrow,
    const float* __restrict__ v, float* __restrict__ out)
{
    const int lane = threadIdx.x & 63;
    const int r = blockIdx.x * 4 + (threadIdx.x >> 6);
    if (r >= *nrow) return;
    const int row = rowlist[r];
    const float* h = H + (size_t)row * CD;
    float4 a0 = *(const float4*)(h + lane * 8);
    float4 a1 = *(const float4*)(h + lane * 8 + 4);
    float4 b0 = *(const float4*)(v + lane * 8);
    float4 b1 = *(const float4*)(v + lane * 8 + 4);
    float sv = a0.x * b0.x + a0.y * b0.y + a0.z * b0.z + a0.w * b0.w
             + a1.x * b1.x + a1.y * b1.y + a1.z * b1.z + a1.w * b1.w;
#pragma unroll
    for (int o = 32; o; o >>= 1) sv += __shfl_xor(sv, o, 64);
    if (lane == 0) out[row] = sv;
}

// ========== wa_gemv6 ==========
__global__ __launch_bounds__(256) void wa_gemv6(
    const float* __restrict__ W6, const float* __restrict__ a6, float* __restrict__ wa)
{
    const int layer = blockIdx.y;
    const int lane = threadIdx.x & 63;
    const int r = blockIdx.x * 4 + (threadIdx.x >> 6);
    const float* Wr = W6 + (size_t)layer * CDCD + (size_t)r * CD;
    const float* ah = a6 + layer * 2 * CD + CD;
    float4 a0 = *(const float4*)(Wr + lane * 8);
    float4 a1 = *(const float4*)(Wr + lane * 8 + 4);
    float4 b0 = *(const float4*)(ah + lane * 8);
    float4 b1 = *(const float4*)(ah + lane * 8 + 4);
    float sv = a0.x * b0.x + a0.y * b0.y + a0.z * b0.z + a0.w * b0.w
             + a1.x * b1.x + a1.y * b1.y + a1.z * b1.z + a1.w * b1.w;
#pragma unroll
    for (int o = 32; o; o >>= 1) sv += __shfl_xor(sv, o, 64);
    if (lane == 0) wa[layer * CD + r] = sv;
}

// ================= parallel CSR build =================
struct Csr6 {
    const int* src[6]; const int* dst[6];
    int* cnt[6]; int* off[6]; int* cur[6]; int* srcs[6];
    int nd[6]; int base[6]; int ecum[7];
};

__global__ __launch_bounds__(256) void zero_ints(int* __restrict__ p, int n)
{
    for (int i = blockIdx.x * 256 + threadIdx.x; i < n; i += gridDim.x * 256)
        p[i] = 0;
}

__global__ __launch_bounds__(256) void csr_hist(Csr6 G)
{
    const int total = G.ecum[6];
    for (int idx = blockIdx.x * 256 + threadIdx.x; idx < total; idx += gridDim.x * 256) {
        int g = 0;
        while (idx >= G.ecum[g + 1]) g++;
        int e = idx - G.ecum[g];
        atomicAdd(&G.cnt[g][G.dst[g][e] - G.base[g]], 1);
    }
}

__global__ __launch_bounds__(1024) void csr_scan(Csr6 G)
{
    __shared__ int wsum[16];
    const int g = blockIdx.x;
    const int tid = threadIdx.x, lane = tid & 63, wid = tid >> 6;
    const int n = G.nd[g];
    int* cnt = G.cnt[g];
    int* off = G.off[g];
    int* cur = G.cur[g];

    int running = 0;
    for (int base = 0; base < n; base += 1024) {
        int idx = base + tid;
        int v0 = (idx < n) ? cnt[idx] : 0;
        int v = v0;
#pragma unroll
        for (int dlt = 1; dlt < 64; dlt <<= 1) {
            int t = __shfl_up(v, dlt, 64);
            if (lane >= dlt) v += t;
        }
        if (lane == 63) wsum[wid] = v;
        __syncthreads();
        if (wid == 0) {
            int wv = (lane < 16) ? wsum[lane] : 0;
#pragma unroll
            for (int dlt = 1; dlt < 16; dlt <<= 1) {
                int t = __shfl_up(wv, dlt, 64);
                if (lane >= dlt) wv += t;
            }
            if (lane < 16) wsum[lane] = wv;
        }
        __syncthreads();
        int wprefix = (wid > 0) ? wsum[wid - 1] : 0;
        int chunk_total = wsum[15];
        int excl = running + wprefix + (v - v0);
        if (idx < n) { off[idx] = excl; cur[idx] = excl; }
        running += chunk_total;
        __syncthreads();
    }
    if (tid == 0) off[n] = running;
}

__global__ __launch_bounds__(256) void csr_scatter(Csr6 G)
{
    const int total = G.ecum[6];
    for (int idx = blockIdx.x * 256 + threadIdx.x; idx < total; idx += gridDim.x * 256) {
        int g = 0;
        while (idx >= G.ecum[g + 1]) g++;
        int e = idx - G.ecum[g];
        int dl = G.dst[g][e] - G.base[g];
        int pos = atomicAdd(&G.cur[g][dl], 1);
        G.srcs[g][pos] = G.src[g][e];
    }
}

__global__ void mark_qsel(const int* __restrict__ qid, int* __restrict__ qsel)
{
    qsel[qid[threadIdx.x]] = 1;
}

// users of interest: user_id rows (into umark/list) + usel flag
__global__ void mark_user(const int* __restrict__ uid, int* __restrict__ usel,
                          int* __restrict__ umark, int* __restrict__ list,
                          int* __restrict__ nlist)
{
    int u = uid[threadIdx.x];
    usel[u] = 1;
    if (atomicExch(&umark[u], 1) == 0)
        list[atomicAdd(nlist, 1)] = u;
}

// l5 sources: eu edges (src user-node, dst question) with dst in qsel
__global__ __launch_bounds__(256) void mark_l5(
    const int* __restrict__ esrc, const int* __restrict__ edst, int ne,
    const int* __restrict__ qsel, int* __restrict__ umark,
    int* __restrict__ list, int* __restrict__ nlist)
{
    for (int e = blockIdx.x * 256 + threadIdx.x; e < ne; e += gridDim.x * 256) {
        if (qsel[edst[e]]) {
            int u = esrc[e] - QN;
            if (atomicExch(&umark[u], 1) == 0)
                list[atomicAdd(nlist, 1)] = u;
        }
    }
}

// f2-l4 sources: ue edges (src question, dst user-node) with dst user in usel
__global__ __launch_bounds__(256) void mark_l4(
    const int* __restrict__ esrc, const int* __restrict__ edst, int ne,
    const int* __restrict__ usel, int* __restrict__ qmark,
    int* __restrict__ qlist, int* __restrict__ nq)
{
    for (int e = blockIdx.x * 256 + threadIdx.x; e < ne; e += gridDim.x * 256) {
        if (usel[edst[e] - QN]) {
            int q = esrc[e];
            if (atomicExch(&qmark[q], 1) == 0)
                qlist[atomicAdd(nq, 1)] = q;
        }
    }
}

// ================= GAT aggregate =================
// node = sel?sel[b]:b. dd index: dv_node? node : b. out row: scatter_out? node : b.
// nlimit (device count) caps active blocks.
__global__ __launch_bounds__(256) void gat_aggregate(
    const int* __restrict__ off, const int* __restrict__ srcs, int src_base,
    const int* __restrict__ sel, const int* __restrict__ nlimit,
    int scatter_out, int dv_node,
    const float* __restrict__ z, const float* __restrict__ s,
    const float* __restrict__ dvals,
    const float* __restrict__ base, float* __restrict__ out)
{
    const int b = blockIdx.x;
    if (nlimit && b >= *nlimit) return;
    const int node = sel ? sel[b] : b;
    const int orow = scatter_out ? node : b;
    const int tid = threadIdx.x;
    const int lane = tid & 63, wid = tid >> 6;
    const int beg = off[node], end = off[node + 1];

    float2 bacc = base ? *(const float2*)(base + (size_t)node * CD + tid * 2)
                       : make_float2(0.f, 0.f);
    if (beg == end) {
        *(float2*)(out + (size_t)orow * CD + tid * 2) = bacc;
        return;
    }
    const float dd = dvals[dv_node ? node : b];

    float m = -1e30f, den = 0.f;
    for (int e = beg + tid; e < end; e += 256) {
        float sc = s[srcs[e] - src_base] + dd;
        sc = sc > 0.f ? sc : 0.01f * sc;
        if (sc > m) { den = den * __expf(m - sc) + 1.f; m = sc; }
        else den += __expf(sc - m);
    }
#pragma unroll
    for (int o = 32; o; o >>= 1) {
        float om = __shfl_xor(m, o, 64);
        float od = __shfl_xor(den, o, 64);
        float nm = fmaxf(m, om);
        den = den * __expf(m - nm) + od * __expf(om - nm);
        m = nm;
    }
    __shared__ float wm[4], wd[4];
    __shared__ float alpha_s[256];
    __shared__ int   src_s[256];
    if (lane == 0) { wm[wid] = m; wd[wid] = den; }
    __syncthreads();
    float M = fmaxf(fmaxf(wm[0], wm[1]), fmaxf(wm[2], wm[3]));
    float Dn = wd[0] * __expf(wm[0] - M) + wd[1] * __expf(wm[1] - M)
             + wd[2] * __expf(wm[2] - M) + wd[3] * __expf(wm[3] - M);
    float invD = 1.f / Dn;

    for (int c0 = beg; c0 < end; c0 += 256) {
        int e = c0 + tid;
        float al = 0.f; int sr = 0;
        if (e < end) {
            sr = srcs[e] - src_base;
            float sc = s[sr] + dd;
            sc = sc > 0.f ? sc : 0.01f * sc;
            al = __expf(sc - M) * invD;
        }
        __syncthreads();
        alpha_s[tid] = al; src_s[tid] = sr;
        __syncthreads();
        int cc = min(256, end - c0);
        for (int jj = 0; jj < cc; jj++) {
            const float* zr = z + (size_t)src_s[jj] * CD;
            float a = alpha_s[jj];
            float2 v = *(const float2*)(zr + tid * 2);
            bacc.x = fmaf(a, v.x, bacc.x);
            bacc.y = fmaf(a, v.y, bacc.y);
        }
    }
    *(float2*)(out + (size_t)orow * CD + tid * 2) = bacc;
}

// ================= attention fuse kn =================
__global__ __launch_bounds__(256) void fuse_kn(
    const float* __restrict__ kn, const float* __restrict__ kd,
    const float* __restrict__ ku, const float* __restrict__ Dm,
    const float* __restrict__ aw, const float* __restrict__ ab, float* __restrict__ out)
{
    const int i = blockIdx.x, tid = threadIdx.x;
    const int lane = tid & 63, wid = tid >> 6;
    const size_t ro = (size_t)i * CD + tid * 2;
    const int c = tid * 2;
    float2 vkn = *(const float2*)(kn + ro);
    float2 v1  = *(const float2*)(kd + ro);
    float2 v2  = *(const float2*)(ku + ro);
    float2 v3  = *(const float2*)(Dm + ro);
    float p1 = vkn.x*aw[c]      + vkn.y*aw[c+1]      + v1.x*aw[CD+c]      + v1.y*aw[CD+c+1];
    float p2 = vkn.x*aw[1024+c] + vkn.y*aw[1024+c+1] + v2.x*aw[1024+CD+c] + v2.y*aw[1024+CD+c+1];
    float p3 = vkn.x*aw[2048+c] + vkn.y*aw[2048+c+1] + v3.x*aw[2048+CD+c] + v3.y*aw[2048+CD+c+1];
#pragma unroll
    for (int o = 32; o; o >>= 1) {
        p1 += __shfl_xor(p1, o, 64); p2 += __shfl_xor(p2, o, 64); p3 += __shfl_xor(p3, o, 64);
    }
    __shared__ float r1[4], r2[4], r3[4];
    if (lane == 0) { r1[wid] = p1; r2[wid] = p2; r3[wid] = p3; }
    __syncthreads();
    float s1 = r1[0]+r1[1]+r1[2]+r1[3] + ab[0];
    float s2 = r2[0]+r2[1]+r2[2]+r2[3] + ab[1];
    float s3 = r3[0]+r3[1]+r3[2]+r3[3] + ab[2];
    float mm = fmaxf(s1, fmaxf(s2, s3));
    float e1 = __expf(s1-mm), e2 = __expf(s2-mm), e3 = __expf(s3-mm);
    float inv = 1.f / (e1 + e2 + e3);
    float w1 = e1*inv, w2 = e2*inv, w3 = e3*inv;
    float2 o_;
    o_.x = vkn.x + w1*v1.x + w2*v2.x + w3*v3.x;
    o_.y = vkn.y + w1*v1.y + w2*v2.y + w3*v3.y;
    *(float2*)(out + ro) = o_;
}

// ================= attention fuse ex =================
__global__ __launch_bounds__(256) void fuse_ex(
    const float* __restrict__ ex, const int* __restrict__ sel,
    const float* __restrict__ Bq, const float* __restrict__ Cq,
    const float* __restrict__ aw, const float* __restrict__ ab, float* __restrict__ out)
{
    const int i = blockIdx.x, tid = threadIdx.x;
    const int lane = tid & 63, wid = tid >> 6;
    const int exrow = sel ? sel[i] : i;
    const size_t eo = (size_t)exrow * CD + tid * 2;
    const size_t ro = (size_t)i * CD + tid * 2;
    const int c = tid * 2;
    float2 ve = *(const float2*)(ex + eo);
    float2 vb = *(const float2*)(Bq + ro);
    float2 vc = *(const float2*)(Cq + ro);
    const float* a3 = aw + 3 * 2 * CD;
    const float* a4 = aw + 4 * 2 * CD;
    float p1 = ve.x*a3[c] + ve.y*a3[c+1] + vb.x*a3[CD+c] + vb.y*a3[CD+c+1];
    float p2 = ve.x*a4[c] + ve.y*a4[c+1] + vc.x*a4[CD+c] + vc.y*a4[CD+c+1];
#pragma unroll
    for (int o = 32; o; o >>= 1) { p1 += __shfl_xor(p1, o, 64); p2 += __shfl_xor(p2, o, 64); }
    __shared__ float r1[4], r2[4];
    if (lane == 0) { r1[wid] = p1; r2[wid] = p2; }
    __syncthreads();
    float t1 = r1[0]+r1[1]+r1[2]+r1[3] + ab[3];
    float t2 = r2[0]+r2[1]+r2[2]+r2[3] + ab[4];
    float mm = fmaxf(t1, t2);
    float e1 = __expf(t1-mm), e2 = __expf(t2-mm);
    float inv = 1.f / (e1 + e2);
    float w1 = e1*inv, w2 = e2*inv;
    float2 o_;
    o_.x = ve.x + w1*vb.x + w2*vc.x;
    o_.y = ve.y + w1*vb.y + w2*vc.y;
    *(float2*)(out + ro) = o_;
}

// ===== final prediction (q_table-sparse) =====
__global__ __launch_bounds__(256) void final_pred(
    const float* __restrict__ sP, const float* __restrict__ kP,
    const float* __restrict__ dP, const float* __restrict__ kD,
    const float* __restrict__ W3, const float* __restrict__ b3,
    const float* __restrict__ q_table, const int* __restrict__ qid,
    float* __restrict__ out)
{
    const int b = blockIdx.x;
    const int tid = threadIdx.x, lane = tid & 63, wid = tid >> 6;
    __shared__ int   sidx[CD];
    __shared__ float sqv[CD];
    __shared__ int   snn;
    __shared__ float scnt[4], sacc[4];
    if (tid == 0) snn = 0;
    __syncthreads();
    const float* qrow = q_table + (size_t)qid[b] * CD;
    float cnt = 0.f;
    for (int i = tid; i < CD; i += 256) {
        float qv = qrow[i];
        if (qv != 0.f) {
            int p = atomicAdd(&snn, 1);
            sidx[p] = i; sqv[p] = qv;
            cnt += qv;
        }
    }
#pragma unroll
    for (int o = 32; o; o >>= 1) cnt += __shfl_xor(cnt, o, 64);
    if (lane == 0) scnt[wid] = cnt;
    __syncthreads();
    const int nn = snn;
    const float bb = b3[0];
    const float* sPr = sP + (size_t)b * CD;
    const float* dPr = dP + (size_t)b * CD;
    float acc = 0.f;
    for (int t = wid; t < nn; t += 4) {
        const int i = sidx[t];
        const float* kPr = kP + (size_t)i * CD;
        const float* kDr = kD + (size_t)i * CD;
        float o = 0.f;
#pragma unroll
        for (int p = 0; p < 8; p++) {
            int j = lane + (p << 6);
            float pv = sPr[j] + kPr[j];
            float dv = dPr[j] + kDr[j];
            float s1 = 1.f / (1.f + __expf(-pv));
            float s2 = 1.f / (1.f + __expf(-dv));
            o += (s1 - s2) * W3[j];
        }
#pragma unroll
        for (int ofs = 32; ofs; ofs >>= 1) o += __shfl_xor(o, ofs, 64);
        if (lane == 0) acc += sqv[t] / (1.f + __expf(-(o + bb)));
    }
    if (lane == 0) sacc[wid] = acc;
    __syncthreads();
    if (tid == 0)
        out[b] = (sacc[0] + sacc[1] + sacc[2] + sacc[3])
               / (scnt[0] + scnt[1] + scnt[2] + scnt[3]);
}

// ================= host orchestration =================
#define EXPAD 8192
#define STUPAD 20224

extern "C" void kernel_launch(void* const* d_in, const int* in_sizes, int n_in,
                              void* d_out, int out_size, void* d_ws, size_t ws_size,
                              hipStream_t stream)
{
    const int*   user_id      = (const int*)d_in[0];
    const int*   question_id  = (const int*)d_in[1];
    const float* q_table      = (const float*)d_in[2];
    const int*   e_dir        = (const int*)d_in[3];
    const int*   e_und        = (const int*)d_in[4];
    const int*   e_ke         = (const int*)d_in[5];
    const int*   e_ek         = (const int*)d_in[6];
    const int*   e_ue         = (const int*)d_in[7];
    const int*   e_eu         = (const int*)d_in[8];
    const float* user_emb     = (const float*)d_in[9];
    const float* question_emb = (const float*)d_in[10];
    const float* concept_emb  = (const float*)d_in[11];
    const float* gat_W        = (const float*)d_in[12];
    const float* gat_a        = (const float*)d_in[13];
    const float* attn_w       = (const float*)d_in[14];
    const float* attn_b       = (const float*)d_in[15];
    const float* W1           = (const float*)d_in[16];
    const float* W2           = (const float*)d_in[17];
    const float* W3           = (const float*)d_in[18];
    const float* b3           = (const float*)d_in[19];
    float* out = (float*)d_out;

    char* wptr = (char*)d_ws;
    auto alloc = [&](size_t bytes) -> void* {
        void* p = (void*)wptr;
        wptr += (bytes + 255) & ~(size_t)255;
        return p;
    };

    float* zone = (float*)alloc((size_t)UN * CD * 4);
    float* z2 = zone;
    float* z4 = zone + (size_t)QN * CD;
    float* z5 = zone;
    float* z0 = (float*)alloc((size_t)CD * CD * 4);
    float* z1 = (float*)alloc((size_t)CD * CD * 4);
    float* z3 = (float*)alloc((size_t)CD * CD * 4);

    float* s0 = (float*)alloc((size_t)CD * 4);
    float* s1 = (float*)alloc((size_t)CD * 4);
    float* s2 = (float*)alloc((size_t)QN * 4);
    float* s3 = (float*)alloc((size_t)CD * 4);
    float* s4 = (float*)alloc((size_t)QN * 4);
    float* s5 = (float*)alloc((size_t)UN * 4);
    float* dv0 = (float*)alloc((size_t)CD * 4);
    float* dv1 = (float*)alloc((size_t)CD * 4);
    float* dv2 = (float*)alloc((size_t)CD * 4);
    float* dv3 = (float*)alloc((size_t)QN * 4);
    float* dv4 = (float*)alloc((size_t)UN * 4);
    float* dv5 = (float*)alloc((size_t)QN * 4);
    float* wa  = (float*)alloc((size_t)6 * CD * 4);

    float* kn1  = (float*)alloc((size_t)CD * CD * 4);
    float* ex1  = (float*)alloc((size_t)QN * CD * 4);
    float* stu1 = (float*)alloc((size_t)UN * CD * 4);
    float* kn2  = (float*)alloc((size_t)CD * CD * 4);
    float* kdir = (float*)alloc((size_t)CD * CD * 4);
    float* kund = (float*)alloc((size_t)CD * CD * 4);
    float* Dm   = (float*)alloc((size_t)CD * CD * 4);
    float* Bq   = (float*)alloc((size_t)QN * CD * 4);
    float* Cq   = (float*)alloc((size_t)QN * CD * 4);
    float* eb   = (float*)alloc((size_t)BATCHN * CD * 4);
    float* sb   = (float*)alloc((size_t)BATCHN * CD * 4);
    float* sP   = (float*)alloc((size_t)BATCHN * CD * 4);
    float* dP   = (float*)alloc((size_t)BATCHN * CD * 4);
    float* kP   = (float*)alloc((size_t)CD * CD * 4);
    float* kD   = (float*)alloc((size_t)CD * CD * 4);

    // split-bf16 buffers
    u16* expH  = (u16*)alloc((size_t)64 * EXPAD * 8 * 2);
    u16* expL  = (u16*)alloc((size_t)64 * EXPAD * 8 * 2);
    u16* stupH = (u16*)alloc((size_t)64 * STUPAD * 8 * 2);
    u16* stupL = (u16*)alloc((size_t)64 * STUPAD * 8 * 2);
    u16* BpH[5]; u16* BpL[5];
    for (int i = 0; i < 5; i++) {
        BpH[i] = (u16*)alloc((size_t)64 * CD * 8 * 2);
        BpL[i] = (u16*)alloc((size_t)64 * CD * 8 * 2);
    }

    static const int g_ne[6]   = {4096, 8192, 40000, 40000, 100000, 100000};
    static const int g_nd[6]   = {512, 512, 512, QN, UN, QN};
    static const int g_base[6] = {0, 0, QN, 0, QN, 0};
    const int* g_edges[6] = {e_dir, e_und, e_ke, e_ek, e_ue, e_eu};

    // zeroed region: cnt6 | qsel | umark | nlist | usel | qmark | nq2
    int cnt_total = 0;
    for (int g = 0; g < 6; g++) cnt_total += g_nd[g];
    int* zbase = (int*)alloc((size_t)(cnt_total + QN + UN + 1 + UN + QN + 1) * 4);
    int* cnt6[6];
    {
        int o = 0;
        for (int g = 0; g < 6; g++) { cnt6[g] = zbase + o; o += g_nd[g]; }
    }
    int* qsel   = zbase + cnt_total;
    int* umark  = qsel + QN;
    int* nlist  = umark + UN;
    int* usel   = nlist + 1;
    int* qmark  = usel + UN;
    int* nq2    = qmark + QN;
    const int ZTOT = cnt_total + QN + UN + 1 + UN + QN + 1;

    int* cur6   = (int*)alloc((size_t)cnt_total * 4);
    int* list   = (int*)alloc((size_t)UN * 4);
    int* qlist2 = (int*)alloc((size_t)QN * 4);
    int* off[6]; int* srcs[6];
    for (int g = 0; g < 6; g++) {
        off[g]  = (int*)alloc((size_t)(g_nd[g] + 1) * 4);
        srcs[g] = (int*)alloc((size_t)g_ne[g] * 4);
    }

    Csr6 G;
    {
        int o = 0, ec = 0;
        for (int g = 0; g < 6; g++) {
            G.src[g] = g_edges[g];
            G.dst[g] = g_edges[g] + g_ne[g];
            G.cnt[g] = cnt6[g];
            G.off[g] = off[g];
            G.cur[g] = cur6 + o;
            G.srcs[g] = srcs[g];
            G.nd[g] = g_nd[g];
            G.base[g] = g_base[g];
            G.ecum[g] = ec;
            o += g_nd[g]; ec += g_ne[g];
        }
        G.ecum[6] = ec;
    }

    zero_ints<<<128, 256, 0, stream>>>(zbase, ZTOT);
    csr_hist<<<512, 256, 0, stream>>>(G);
    csr_scan<<<6, 1024, 0, stream>>>(G);
    csr_scatter<<<512, 256, 0, stream>>>(G);
    mark_qsel<<<1, BATCHN, 0, stream>>>(question_id, qsel);
    mark_user<<<1, BATCHN, 0, stream>>>(user_id, usel, umark, list, nlist);
    mark_l5<<<200, 256, 0, stream>>>(e_eu, e_eu + 100000, 100000, qsel, umark, list, nlist);
    mark_l4<<<200, 256, 0, stream>>>(e_ue, e_ue + 100000, 100000, usel, qmark, qlist2, nq2);

    // pre-convert the 5 weight matrices used by MFMA GEMMs: f0:{l2,l4,l5}, f1:{l2}
    {
        WcJobs wj;
        const int fl[5][2] = {{0,2},{0,4},{0,5},{1,2},{1,4}};
        for (int i = 0; i < 5; i++) {
            wj.src[i] = gat_W + (size_t)(fl[i][0] * 6 + fl[i][1]) * CDCD;
            wj.h[i] = BpH[i]; wj.l[i] = BpL[i];
        }
        conv_bw<<<dim3(2, 64, 5), 256, 0, stream>>>(wj);
    }

    auto gemm_s = [&](const float* A, int n, const int* rl, const int* nr,
                      const float* B0, float* C0, const float* B1, float* C1, int gx) {
        dim3 g(gx, B1 ? 16 : 8);
        gemm_f32_s<<<g, 256, 0, stream>>>(A, n, rl, nr, B0, C0, B1, C1);
    };
    auto dots = [&](const float* H, const int* sel, const float* v, float* o, int n) {
        dot_rows<<<(n + 3) / 4, 256, 0, stream>>>(H, sel, v, o, n);
    };
    auto agg = [&](int g, int src_base, const int* sel, const int* nlim, int sc, int dvn,
                   const float* z, const float* s, const float* dv,
                   const float* base, float* o, int nblk) {
        gat_aggregate<<<nblk, 256, 0, stream>>>(off[g], srcs[g], src_base, sel, nlim,
                                                sc, dvn, z, s, dv, base, o);
    };

    auto run_fusion = [&](int f, const float* kn, const float* ex, const float* stu,
                          const int* selq, const int* selu,
                          float* kn_o, float* ex_o, float* stu_o) {
        const float* Wf  = gat_W  + (size_t)f * 6 * CDCD;
        const float* af  = gat_a  + (size_t)f * 6 * 2 * CD;
        const float* awf = attn_w + (size_t)f * 5 * 2 * CD;
        const float* abf = attn_b + (size_t)f * 5;
        const int bp = f * 3;

        conv_a<<<dim3(EXPAD / 256, 64), 256, 0, stream>>>(ex, expH, expL, QN);
        if (!selq)
            conv_a<<<dim3(STUPAD / 256, 64), 256, 0, stream>>>(stu, stupH, stupL, UN);

        wa_gemv6<<<dim3(128, 6), 256, 0, stream>>>(Wf, af, wa);

        // l0 + l1 (A = kn, small fp32 dual)
        gemm_s(kn, CD, nullptr, nullptr, Wf + 0 * CDCD, z0, Wf + 1 * CDCD, z1, CD / SBM);
        dots(z0, nullptr, af + 0 * 2 * CD, s0, CD);
        dots(z1, nullptr, af + 1 * 2 * CD, s1, CD);
        dots(kn, nullptr, wa + 0 * CD, dv0, CD);
        dots(kn, nullptr, wa + 1 * CD, dv1, CD);
        agg(0, 0, nullptr, nullptr, 0, 0, z0, s0, dv0, nullptr, kdir, CD);
        agg(1, 0, nullptr, nullptr, 0, 0, z1, s1, dv1, nullptr, kund, CD);

        // l2 (A = ex, MFMA; dual with l4 in fusion 1 only)
        if (!selq) {
            gemm_bf3<<<dim3((QN + 127) / 128, 8), 256, 0, stream>>>(
                expH, expL, QN, EXPAD,
                BpH[bp + 0], BpL[bp + 0], z2,
                BpH[bp + 1], BpL[bp + 1], z4);
        } else {
            gemm_bf3<<<dim3((QN + 127) / 128, 4), 256, 0, stream>>>(
                expH, expL, QN, EXPAD,
                BpH[bp + 0], BpL[bp + 0], z2,
                nullptr, nullptr, nullptr);
            // f2 l4: only ~640 question rows feed the 128 selected users
            gemm_s(ex, 0, qlist2, nq2, Wf + 4 * CDCD, z4, nullptr, nullptr, QN / SBM);
        }
        dots(z2, nullptr, af + 2 * 2 * CD, s2, QN);
        dots(kn, nullptr, wa + 2 * CD, dv2, CD);
        agg(2, 0, nullptr, nullptr, 0, 0, z2, s2, dv2, nullptr, Dm, CD);

        // l3 (A = kn, small fp32)
        gemm_s(kn, CD, nullptr, nullptr, Wf + 3 * CDCD, z3, nullptr, nullptr, CD / SBM);
        dots(z3, nullptr, af + 3 * 2 * CD, s3, CD);
        if (!selq) {
            dots(ex, nullptr, wa + 3 * CD, dv3, QN);
            agg(3, QN, nullptr, nullptr, 0, 0, z3, s3, dv3, nullptr, Bq, QN);
        } else {
            dots(ex, selq, wa + 3 * CD, dv3, BATCHN);
            agg(3, QN, selq, nullptr, 0, 0, z3, s3, dv3, nullptr, Bq, BATCHN);
        }

        // l4 aggregation
        if (!selq) {
            // fusion 1: stu1 only needed at `list` rows (user_id ∪ f2-l5 sources)
            dots(z4, nullptr, af + 4 * 2 * CD, s4, QN);
            dot_rows_gather<<<(UN + 3) / 4, 256, 0, stream>>>(stu, list, nlist,
                                                              wa + 4 * CD, dv4);
            agg(4, 0, list, nlist, 1, 1, z4, s4, dv4, stu, stu_o, UN);
        } else {
            dot_rows_gather<<<(QN + 3) / 4, 256, 0, stream>>>(z4, qlist2, nq2,
                                                              af + 4 * 2 * CD, s4);
            dots(stu, selu, wa + 4 * CD, dv4, BATCHN);
            agg(4, 0, selu, nullptr, 0, 0, z4, s4, dv4, stu, stu_o, BATCHN);
        }

        // l5 (A = stu) — z5 aliases zone, runs after l2/l4 aggregates consumed it
        if (!selq) {
            gemm_bf3<<<dim3((UN + 127) / 128, 4), 256, 0, stream>>>(
                stupH, stupL, UN, STUPAD,
                BpH[bp + 2], BpL[bp + 2], z5,
                nullptr, nullptr, nullptr);
            dots(z5, nullptr, af + 5 * 2 * CD, s5, UN);
            dots(ex, nullptr, wa + 5 * CD, dv5, QN);
            agg(5, QN, nullptr, nullptr, 0, 0, z5, s5, dv5, nullptr, Cq, QN);
        } else {
            gemm_s(stu, 0, list, nlist, Wf + 5 * CDCD, z5, nullptr, nullptr, UN / SBM);
            dot_rows_gather<<<(UN + 3) / 4, 256, 0, stream>>>(z5, list, nlist,
                                                              af + 5 * 2 * CD, s5);
            dots(ex, selq, wa + 5 * CD, dv5, BATCHN);
            agg(5, QN, selq, nullptr, 0, 0, z5, s5, dv5, nullptr, Cq, BATCHN);
        }

        fuse_kn<<<CD, 256, 0, stream>>>(kn, kdir, kund, Dm, awf, abf, kn_o);
        fuse_ex<<<selq ? BATCHN : QN, 256, 0, stream>>>(ex, selq, Bq, Cq, awf, abf, ex_o);
    };

    run_fusion(0, concept_emb, question_emb, user_emb, nullptr, nullptr,
               kn1, ex1, stu1);
    run_fusion(1, kn1, ex1, stu1, question_id, user_id,
               kn2, eb, sb);

    // prediction head (small fp32)
    gemm_s(sb, BATCHN, nullptr, nullptr, W1, sP, nullptr, nullptr, BATCHN / SBM);
    gemm_s(eb, BATCHN, nullptr, nullptr, W2, dP, nullptr, nullptr, BATCHN / SBM);
    gemm_s(kn2, CD, nullptr, nullptr, W1 + (size_t)CDCD, kP, W2 + (size_t)CDCD, kD, CD / SBM);
    final_pred<<<BATCHN, 256, 0, stream>>>(sP, kP, dP, kD, W3, b3, q_table, question_id, out);
}